// Round 2
// baseline (1036.298 us; speedup 1.0000x reference)
//
#include <hip/hip_runtime.h>
#include <hip/hip_bf16.h>

// ForwardSumLossWithBlank: CTC forward (alpha) loss, blank=0, targets=arange(text_len).
// B=32 samples, T=2000 mel frames, C=400 classes. Output: scalar mean loss (fp32).
//
// Pass A: rsum[b,t] = 1 / sum_{c < text_len[b]} exp(logits[b,t,c])   (softmax denom)
// Pass B: one wave per sample, linear-domain scaled CTC recursion, states in registers,
//         logit rows prefetched 6 deep into LDS via global_load_lds + counted vmcnt.
// Pass C: deterministic mean over 32 per-sample losses.

static constexpr int B_ = 32;
static constexpr int T_ = 2000;
static constexpr int C_ = 400;

__device__ __forceinline__ void gload_lds16(const float* g, float* l) {
    // 16 B per lane: LDS dest = base + lane*16 (wave-uniform base), global src per-lane.
    __builtin_amdgcn_global_load_lds((const __attribute__((address_space(1))) void*)g,
                                     (__attribute__((address_space(3))) void*)l, 16, 0, 0);
}

// ---------------- Pass A: per-row softmax denominators ----------------
__global__ __launch_bounds__(256) void k_rowstats(const float* __restrict__ logits,
                                                  const int* __restrict__ text_lens,
                                                  float* __restrict__ rsum) {
    const int lane = threadIdx.x & 63;
    const int row  = blockIdx.x * 4 + (threadIdx.x >> 6);   // grid sized exactly: B*T/4 blocks
    const int b    = row / T_;
    const int tl   = text_lens[b];
    const float* __restrict__ r = logits + (size_t)row * C_;
    float s = 0.f;
#pragma unroll
    for (int j = 0; j < 7; ++j) {
        const int c = j * 64 + lane;
        if (c < tl) s += __expf(r[c]);          // c < tl <= 400 -> in bounds
    }
#pragma unroll
    for (int off = 32; off; off >>= 1) s += __shfl_xor(s, off);
    if (lane == 0) rsum[row] = 1.0f / s;
}

// ---------------- Pass B: per-sample CTC recursion (1 wave/block) ----------------
// Pair k holds states (2k, 2k+1); pair tl holds only the final even state s_end=2*tl.
//   e            = a[2k] + a[2k-1]
//   new a[2k]    = e * p_blank
//   new a[2k+1]  = (a[2k+1] + e) * p_k        (covers the CTC skip transition)
template <int PP>
__device__ __forceinline__ void ctc_run(const float* __restrict__ Lb,
                                        const float* __restrict__ rsum_b,
                                        int tl, int ml, float* __restrict__ loss_out,
                                        float (*Lrow)[512], float* Rs) {
    const int lane = threadIdx.x;

    // --- prologue: stage rsum row (8000 B) + logit rows 0..6 into LDS ---
#pragma unroll
    for (int i = 0; i < 8; ++i) {
        const int chunk = i * 64 + lane;                  // 16B chunks, 500 total
        if (chunk < 500) gload_lds16(rsum_b + chunk * 4, &Rs[i * 256]);
    }
#pragma unroll
    for (int r = 0; r < 7; ++r) {
        const float* gp = Lb + (size_t)r * C_;
        gload_lds16(gp + lane * 4, &Lrow[r][0]);                    // 1024 B
        if (lane < 36) gload_lds16(gp + 256 + lane * 4, &Lrow[r][256]);  // 576 B (row=1600 B exact)
    }
    asm volatile("s_waitcnt vmcnt(0)" ::: "memory");
    __builtin_amdgcn_sched_barrier(0);

    const float M0    = 1e28f;
    const float LOGM0 = 64.47238260f;   // ln(1e28)

    // --- init (t = 0): alpha[0] = alpha[1] = p(class 0), pre-scaled by M0 so the
    // first renorm never sees a tiny max (scale = M0/m stays finite forever) ---
    float aeven[PP], aodd[PP];
#pragma unroll
    for (int j = 0; j < PP; ++j) { aeven[j] = 0.f; aodd[j] = 0.f; }
    const int base = lane * PP;
    {
        const float p00 = __expf(Lrow[0][0]) * Rs[0] * M0;
        if (lane == 0) { aeven[0] = p00; aodd[0] = p00; }
    }
    float lognorm = -LOGM0;             // compensates the M0 injected at init

    for (int t = 1; t < ml; ++t) {
        // prefetch row t+6 (clamped; keeps vmcnt count invariant through the tail)
        {
            int tr = t + 6; if (tr > ml - 1) tr = ml - 1;
            const float* gp = Lb + (size_t)tr * C_;
            float* lb = &Lrow[(t + 6) & 7][0];
            gload_lds16(gp + lane * 4, lb);
            if (lane < 36) gload_lds16(gp + 256 + lane * 4, lb + 256);
        }
        // rows t..t+6 in flight (14 loads); wait so row t's 2 loads (oldest) are done
        asm volatile("s_waitcnt vmcnt(12)" ::: "memory");
        __builtin_amdgcn_sched_barrier(0);

        const float* Lr = &Lrow[t & 7][0];
        const float rs  = Rs[t];
        const float p0  = __expf(Lr[0]) * rs;     // blank prob (also label-0 prob)

        float prev = __shfl_up(aodd[PP - 1], 1);  // old odd state of pair base-1
        if (lane == 0) prev = 0.f;
#pragma unroll
        for (int j = 0; j < PP; ++j) {
            const int k = base + j;
            float pk = __expf(Lr[k]) * rs;        // k<512 always in-bounds LDS read
            pk = (k < tl) ? pk : 0.f;             // pair tl & padding: odd state stays 0
            const float oldodd = aodd[j];
            const float e = aeven[j] + prev;
            aeven[j] = e * p0;
            aodd[j]  = (oldodd + e) * pk;
            prev = oldodd;
        }

        // renorm every 4 steps. Two-multiply form (a*inv)*M0 cannot overflow even for
        // pathological m (old single-multiply M0/m produced Inf when m < 3e-11 -> NaN).
        if ((t & 3) == 0) {
            float m = 0.f;
#pragma unroll
            for (int j = 0; j < PP; ++j) m = fmaxf(m, fmaxf(aeven[j], aodd[j]));
#pragma unroll
            for (int off = 32; off; off >>= 1) m = fmaxf(m, __shfl_xor(m, off));
            const float inv = 1.0f / m;
            lognorm += __logf(m) - LOGM0;
#pragma unroll
            for (int j = 0; j < PP; ++j) {
                aeven[j] = (aeven[j] * inv) * M0;
                aodd[j]  = (aodd[j]  * inv) * M0;
            }
        }
    }

    // --- epilogue: ll = log(alpha[2*tl] + alpha[2*tl-1]) + lognorm ---
    float contrib = 0.f;
#pragma unroll
    for (int j = 0; j < PP; ++j) {
        const int k = base + j;
        if (k == tl)     contrib += aeven[j];
        if (k == tl - 1) contrib += aodd[j];
    }
#pragma unroll
    for (int off = 32; off; off >>= 1) contrib += __shfl_xor(contrib, off);
    if (lane == 0) {
        float loss = 0.f;
        if (contrib > 0.f) {
            const float ll = __logf(contrib) + lognorm;
            loss = -ll / (float)tl;
        }
        *loss_out = loss;
    }
}

__global__ __launch_bounds__(64) void k_ctc(const float* __restrict__ logits,
                                            const int* __restrict__ text_lens,
                                            const int* __restrict__ mel_lens,
                                            const float* __restrict__ rsum,
                                            float* __restrict__ losses) {
    __shared__ float Lrow[8][512];   // 8 x 2 KB rolling row buffers
    __shared__ float Rs[2048];       // rsum row (2000 floats)
    const int b  = blockIdx.x;
    const int tl = text_lens[b];
    const int ml = mel_lens[b];
    const float* Lb = logits + (size_t)b * T_ * C_;
    const float* rb = rsum + (size_t)b * T_;
    float* lo = losses + b;
    const int PP = (tl + 1 + 63) >> 6;   // pairs = tl+1, per-lane slots
    switch (PP) {
        case 1: ctc_run<1>(Lb, rb, tl, ml, lo, Lrow, Rs); break;
        case 2: ctc_run<2>(Lb, rb, tl, ml, lo, Lrow, Rs); break;
        case 3: ctc_run<3>(Lb, rb, tl, ml, lo, Lrow, Rs); break;
        case 4: ctc_run<4>(Lb, rb, tl, ml, lo, Lrow, Rs); break;
        case 5: ctc_run<5>(Lb, rb, tl, ml, lo, Lrow, Rs); break;
        case 6: ctc_run<6>(Lb, rb, tl, ml, lo, Lrow, Rs); break;
        default: ctc_run<7>(Lb, rb, tl, ml, lo, Lrow, Rs); break;
    }
}

// ---------------- Pass C: deterministic mean ----------------
__global__ __launch_bounds__(64) void k_final(const float* __restrict__ losses,
                                              float* __restrict__ out) {
    const int lane = threadIdx.x;
    float v = (lane < B_) ? losses[lane] : 0.f;
#pragma unroll
    for (int off = 32; off; off >>= 1) v += __shfl_xor(v, off);
    if (lane == 0) out[0] = v * (1.0f / B_);
}

extern "C" void kernel_launch(void* const* d_in, const int* in_sizes, int n_in,
                              void* d_out, int out_size, void* d_ws, size_t ws_size,
                              hipStream_t stream) {
    const float* logits    = (const float*)d_in[0];   // [B,1,T,C] fp32
    const int*   text_lens = (const int*)d_in[1];     // [B] int32
    const int*   mel_lens  = (const int*)d_in[2];     // [B] int32
    float* rsum   = (float*)d_ws;                     // B*T floats (256 KB)
    float* losses = rsum + (size_t)B_ * T_;           // B floats
    float* out    = (float*)d_out;

    k_rowstats<<<B_ * T_ / 4, 256, 0, stream>>>(logits, text_lens, rsum);
    k_ctc<<<B_, 64, 0, stream>>>(logits, text_lens, mel_lens, rsum, losses);
    k_final<<<1, 64, 0, stream>>>(losses, out);
}

// Round 3
// 764.303 us; speedup vs baseline: 1.3559x; 1.3559x over previous
//
#include <hip/hip_runtime.h>
#include <hip/hip_bf16.h>

// ForwardSumLossWithBlank: CTC forward (alpha) loss, blank=0, targets=arange(text_len).
// B=32, T=2000 mel frames, C=400 classes. Output: scalar mean loss (fp32).
//
// Pass A: ls[b,t] = ln( sum_{c < text_len[b]} exp(logits[b,t,c]) )
// Pass B: one wave per sample. Linear-domain scaled CTC recursion, states in registers.
//   - cross-lane prev via DPP wave_shr:1 (2-cy VALU, not ds_permute)
//   - renorm wave-max via DPP row_shr/row_bcast reduce + readlane
//   - p-row (exp of logits) pipelined one row ahead in registers (pA/pB)
//   - logit rows prefetched 12 deep into a 16-slot LDS ring via global_load_lds,
//     counted s_waitcnt vmcnt(22) (= 11 rows x 2 loads outstanding)
// Pass C: deterministic mean.

static constexpr int B_ = 32;
static constexpr int T_ = 2000;
static constexpr int C_ = 400;
static constexpr int RING = 16;       // LDS row ring slots (power of 2)
static constexpr int LOOKAHEAD = 12;  // rows prefetched ahead; vmcnt literal = 2*(LOOKAHEAD-1)

__device__ __forceinline__ void gload_lds16(const float* g, float* l) {
    // 16 B per lane: LDS dest = base + lane*16 (wave-uniform base), global src per-lane.
    __builtin_amdgcn_global_load_lds((const __attribute__((address_space(1))) void*)g,
                                     (__attribute__((address_space(3))) void*)l, 16, 0, 0);
}

template <int CTRL>
__device__ __forceinline__ float dppmov(float v) {
    // mov_dpp with bound_ctrl=1: invalid-source lanes read 0.
    return __int_as_float(__builtin_amdgcn_update_dpp(
        0, __float_as_int(v), CTRL, 0xF, 0xF, true));
}

// ---------------- Pass A: per-row log-sum-exp denominators (ln s) ----------------
__global__ __launch_bounds__(256) void k_rowstats(const float* __restrict__ logits,
                                                  const int* __restrict__ text_lens,
                                                  float* __restrict__ ls) {
    const int lane = threadIdx.x & 63;
    const int row  = blockIdx.x * 4 + (threadIdx.x >> 6);   // grid = B*T/4 blocks exactly
    const int b    = row / T_;
    const int tl   = text_lens[b];
    const float* __restrict__ r = logits + (size_t)row * C_;
    float s = 0.f;
#pragma unroll
    for (int j = 0; j < 7; ++j) {
        const int c = j * 64 + lane;
        if (c < tl) s += __expf(r[c]);          // c < tl <= 400 -> in bounds
    }
#pragma unroll
    for (int off = 32; off; off >>= 1) s += __shfl_xor(s, off);
    if (lane == 0) ls[row] = __logf(s);
}

// ---------------- Pass B helpers ----------------
__device__ __forceinline__ void prefetch_row(const float* __restrict__ Lb,
                                             float (*Lrow)[512], int t, int ml, int lane) {
    int tr = t; if (tr > ml - 1) tr = ml - 1;   // clamp keeps vmcnt count invariant
    const float* gp = Lb + (size_t)tr * C_;
    float* lb = &Lrow[t & (RING - 1)][0];
    gload_lds16(gp + lane * 4, lb);                           // 1024 B
    if (lane < 36) gload_lds16(gp + 256 + lane * 4, lb + 256); // 576 B (row = 1600 B)
}

template <int PP>
__device__ __forceinline__ void compute_p(const float* __restrict__ Lr, int base, int tl,
                                          float* __restrict__ p) {
    // off critical path (pipelined one row ahead); masking folded in here
    p[0] = __expf(Lr[0]);
#pragma unroll
    for (int j = 0; j < PP; ++j) {
        const int k = base + j;
        const float e = __expf(Lr[k]);          // k < 512: always in-bounds LDS
        p[1 + j] = (k < tl) ? e : 0.f;          // pair tl & padding: odd state stays 0
    }
}

template <int PP>
__device__ __forceinline__ void step_update(const float* __restrict__ p, int base, int tl,
                                            float* __restrict__ aeven, float* __restrict__ aodd,
                                            float& lognorm, bool do_renorm) {
    const float p0 = p[0];
    float prev = dppmov<0x138>(aodd[PP - 1]);   // wave_shr:1 -> lane l gets lane l-1; lane0 = 0
#pragma unroll
    for (int j = 0; j < PP; ++j) {
        const float oldodd = aodd[j];
        const float e = aeven[j] + prev;
        aeven[j] = e * p0;
        aodd[j]  = (oldodd + e) * p[1 + j];
        prev = oldodd;
    }
    if (do_renorm) {
        // wave-max via DPP reduce (identity 0 is safe: alphas >= 0), ~20 cycles
        float m = 0.f;
#pragma unroll
        for (int j = 0; j < PP; ++j) m = fmaxf(m, fmaxf(aeven[j], aodd[j]));
        m = fmaxf(m, dppmov<0x111>(m));   // row_shr:1
        m = fmaxf(m, dppmov<0x112>(m));   // row_shr:2
        m = fmaxf(m, dppmov<0x114>(m));   // row_shr:4
        m = fmaxf(m, dppmov<0x118>(m));   // row_shr:8
        m = fmaxf(m, dppmov<0x142>(m));   // row_bcast:15
        m = fmaxf(m, dppmov<0x143>(m));   // row_bcast:31  -> lane 63 holds wave max
        const float wm = __int_as_float(__builtin_amdgcn_readlane(__float_as_int(m), 63));
        const float inv = 1.0f / wm;
        lognorm += __logf(wm) - 46.0517019f;            // - ln(1e20)
#pragma unroll
        for (int j = 0; j < PP; ++j) {
            aeven[j] = (aeven[j] * inv) * 1e20f;        // two-multiply: cannot overflow
            aodd[j]  = (aodd[j]  * inv) * 1e20f;
        }
    }
}

// ---------------- Pass B: per-sample CTC recursion (1 wave/block) ----------------
// Pair k holds states (2k, 2k+1); pair tl holds only the final even state s_end=2*tl.
//   e = a[2k] + a[2k-1];  a'[2k] = e*p0;  a'[2k+1] = (a[2k+1]+e)*pk
template <int PP>
__device__ __forceinline__ void ctc_run(const float* __restrict__ Lb,
                                        const float* __restrict__ ls_b,
                                        int tl, int ml, float* __restrict__ loss_out,
                                        float (*Lrow)[512], float* LsS) {
    const int lane = threadIdx.x;

    // --- prologue: stage ls row (8000 B) + logit rows 0..LOOKAHEAD into LDS ---
#pragma unroll
    for (int i = 0; i < 8; ++i) {
        const int chunk = i * 64 + lane;                  // 16B chunks, 500 total
        if (chunk < 500) gload_lds16(ls_b + chunk * 4, &LsS[i * 256]);
    }
#pragma unroll
    for (int r = 0; r <= LOOKAHEAD; ++r) prefetch_row(Lb, Lrow, r, ml, lane);
    asm volatile("s_waitcnt vmcnt(0)" ::: "memory");
    __builtin_amdgcn_sched_barrier(0);

    const float M0 = 1e20f, LOGM0 = 46.0517019f;

    float aeven[PP], aodd[PP];
#pragma unroll
    for (int j = 0; j < PP; ++j) { aeven[j] = 0.f; aodd[j] = 0.f; }
    const int base = lane * PP;
    {
        const float a00 = __expf(Lrow[0][0]) * M0;   // raw-domain init, pre-scaled by M0
        if (lane == 0) { aeven[0] = a00; aodd[0] = a00; }
    }
    float lognorm = -LOGM0;
    float lsum = LsS[0];

    float pA[PP + 1], pB[PP + 1];
    compute_p<PP>(&Lrow[1][0], base, tl, pA);        // row 1 resident after prologue

    int t = 1;
    for (;;) {
        // rows t+2..t+LOOKAHEAD allowed outstanding (22 loads) -> row t+1 resident
        prefetch_row(Lb, Lrow, t + LOOKAHEAD, ml, lane);
        asm volatile("s_waitcnt vmcnt(22)" ::: "memory");
        __builtin_amdgcn_sched_barrier(0);
        compute_p<PP>(&Lrow[(t + 1) & (RING - 1)][0], base, tl, pB);  // for t+1 (garbage at t+1>=ml: unused)
        lsum += LsS[t];
        step_update<PP>(pA, base, tl, aeven, aodd, lognorm, (t & 3) == 0);
        ++t; if (t >= ml) break;

        prefetch_row(Lb, Lrow, t + LOOKAHEAD, ml, lane);
        asm volatile("s_waitcnt vmcnt(22)" ::: "memory");
        __builtin_amdgcn_sched_barrier(0);
        compute_p<PP>(&Lrow[(t + 1) & (RING - 1)][0], base, tl, pA);
        lsum += LsS[t];
        step_update<PP>(pB, base, tl, aeven, aodd, lognorm, (t & 3) == 0);
        ++t; if (t >= ml) break;
    }

    // --- epilogue: ll = ln(alpha_raw[2tl] + alpha_raw[2tl-1]) + lognorm - sum(ln s_t) ---
    float contrib = 0.f;
#pragma unroll
    for (int j = 0; j < PP; ++j) {
        const int k = base + j;
        if (k == tl)     contrib += aeven[j];
        if (k == tl - 1) contrib += aodd[j];
    }
#pragma unroll
    for (int off = 32; off; off >>= 1) contrib += __shfl_xor(contrib, off);
    if (lane == 0) {
        float loss = 0.f;
        if (contrib > 0.f) {
            const float ll = __logf(contrib) + lognorm - lsum;
            loss = -ll / (float)tl;
        }
        *loss_out = loss;
    }
}

__global__ __launch_bounds__(64) void k_ctc(const float* __restrict__ logits,
                                            const int* __restrict__ text_lens,
                                            const int* __restrict__ mel_lens,
                                            const float* __restrict__ ls,
                                            float* __restrict__ losses) {
    __shared__ float Lrow[RING][512];   // 16 x 2 KB rolling row buffers (32 KB)
    __shared__ float LsS[2048];         // ln-sum row (2000 floats)
    const int b  = blockIdx.x;
    const int tl = text_lens[b];
    const int ml = mel_lens[b];
    const float* Lb = logits + (size_t)b * T_ * C_;
    const float* lb = ls + (size_t)b * T_;
    float* lo = losses + b;
    const int PP = (tl + 1 + 63) >> 6;   // pairs = tl+1, per-lane slots
    switch (PP) {
        case 1: ctc_run<1>(Lb, lb, tl, ml, lo, Lrow, LsS); break;
        case 2: ctc_run<2>(Lb, lb, tl, ml, lo, Lrow, LsS); break;
        case 3: ctc_run<3>(Lb, lb, tl, ml, lo, Lrow, LsS); break;
        case 4: ctc_run<4>(Lb, lb, tl, ml, lo, Lrow, LsS); break;
        case 5: ctc_run<5>(Lb, lb, tl, ml, lo, Lrow, LsS); break;
        case 6: ctc_run<6>(Lb, lb, tl, ml, lo, Lrow, LsS); break;
        default: ctc_run<7>(Lb, lb, tl, ml, lo, Lrow, LsS); break;
    }
}

// ---------------- Pass C: deterministic mean ----------------
__global__ __launch_bounds__(64) void k_final(const float* __restrict__ losses,
                                              float* __restrict__ out) {
    const int lane = threadIdx.x;
    float v = (lane < B_) ? losses[lane] : 0.f;
#pragma unroll
    for (int off = 32; off; off >>= 1) v += __shfl_xor(v, off);
    if (lane == 0) out[0] = v * (1.0f / B_);
}

extern "C" void kernel_launch(void* const* d_in, const int* in_sizes, int n_in,
                              void* d_out, int out_size, void* d_ws, size_t ws_size,
                              hipStream_t stream) {
    const float* logits    = (const float*)d_in[0];   // [B,1,T,C] fp32
    const int*   text_lens = (const int*)d_in[1];     // [B] int32
    const int*   mel_lens  = (const int*)d_in[2];     // [B] int32
    float* ls     = (float*)d_ws;                     // B*T floats (256 KB)
    float* losses = ls + (size_t)B_ * T_;             // B floats
    float* out    = (float*)d_out;

    k_rowstats<<<B_ * T_ / 4, 256, 0, stream>>>(logits, text_lens, ls);
    k_ctc<<<B_, 64, 0, stream>>>(logits, text_lens, mel_lens, ls, losses);
    k_final<<<1, 64, 0, stream>>>(losses, out);
}

// Round 4
// 341.804 us; speedup vs baseline: 3.0318x; 2.2361x over previous
//
#include <hip/hip_runtime.h>

// ForwardSumLossWithBlank: CTC forward (alpha) loss, blank=0, targets=arange(text_len).
// B=32, T=2000 mel frames, C=400 classes. Output: scalar mean loss (fp32).
//
// Pass A : ls[b,t] = ln( sum_{c < text_len[b]} exp(logits[b,t,c]) )
// Pass A2: lsums[b] = sum_{t < mel_len[b]} ls[b,t]     (hoists the softmax-denominator
//          correction completely out of the serial recursion)
// Pass B : one wave per sample, raw-domain scaled CTC recursion, states in registers.
//          Per-lane operand floats loaded DIRECTLY global->register, 8 rows deep in
//          rotating compile-time-indexed buffers (no LDS, no vmcnt asm, no barriers).
//          Cross-lane prev via DPP wave_shr:1; renorm every 8 steps via DPP max-reduce.
// Pass C : deterministic mean.

static constexpr int B_ = 32;
static constexpr int T_ = 2000;
static constexpr int C_ = 400;
static constexpr float M0f    = 1e10f;
static constexpr float LOGM0f = 23.02585093f;   // ln(1e10)

template <int CTRL>
__device__ __forceinline__ float dppmov(float v) {
    // mov_dpp, bound_ctrl=1: invalid-source lanes read 0 (safe: alphas are >= 0).
    return __int_as_float(__builtin_amdgcn_update_dpp(
        0, __float_as_int(v), CTRL, 0xF, 0xF, true));
}

__device__ __forceinline__ float bcast0(float v) {
    return __int_as_float(__builtin_amdgcn_readfirstlane(__float_as_int(v)));
}

// ---------------- Pass A: per-row log-sum-exp denominators ----------------
__global__ __launch_bounds__(256) void k_rowstats(const float* __restrict__ logits,
                                                  const int* __restrict__ text_lens,
                                                  float* __restrict__ ls) {
    const int lane = threadIdx.x & 63;
    const int row  = blockIdx.x * 4 + (threadIdx.x >> 6);   // grid = B*T/4 exactly
    const int b    = row / T_;
    const int tl   = text_lens[b];
    const float* __restrict__ r = logits + (size_t)row * C_;
    float s = 0.f;
#pragma unroll
    for (int j = 0; j < 7; ++j) {
        const int c = j * 64 + lane;
        if (c < tl) s += __expf(r[c]);          // c < tl <= 400 -> in bounds
    }
#pragma unroll
    for (int off = 32; off; off >>= 1) s += __shfl_xor(s, off);
    if (lane == 0) ls[row] = __logf(s);
}

// ---------------- Pass A2: per-sample sum of ln-denominators ----------------
__global__ __launch_bounds__(256) void k_lsum(const float* __restrict__ ls,
                                              const int* __restrict__ mel_lens,
                                              float* __restrict__ lsums) {
    const int b  = blockIdx.x;
    const int ml = mel_lens[b];
    float s = 0.f;
    for (int i = threadIdx.x; i < ml; i += 256) s += ls[(size_t)b * T_ + i];
#pragma unroll
    for (int off = 32; off; off >>= 1) s += __shfl_xor(s, off);
    __shared__ float ws[4];
    if ((threadIdx.x & 63) == 0) ws[threadIdx.x >> 6] = s;
    __syncthreads();
    if (threadIdx.x == 0) lsums[b] = (ws[0] + ws[1]) + (ws[2] + ws[3]);
}

// ---------------- Pass B ----------------
// Pair k holds states (2k, 2k+1); pair tl holds only the final even state 2*tl.
//   e = a[2k] + a[2k-1];  a'[2k] = e*p0;  a'[2k+1] = (a[2k+1]+e)*pk
template <int PP>
__device__ __forceinline__ void step_update(const float p0, const float* __restrict__ p,
                                            float* __restrict__ aeven, float* __restrict__ aodd) {
    float prev = dppmov<0x138>(aodd[PP - 1]);   // wave_shr:1 -> lane l-1's last oldodd; lane0=0
#pragma unroll
    for (int j = 0; j < PP; ++j) {
        const float oldodd = aodd[j];
        const float e = aeven[j] + prev;
        aeven[j] = e * p0;
        aodd[j]  = (oldodd + e) * p[j];
        prev = oldodd;
    }
}

template <int PP>
__device__ __forceinline__ void renorm(float* __restrict__ aeven, float* __restrict__ aodd,
                                       float& lognorm) {
    float m = 0.f;
#pragma unroll
    for (int j = 0; j < PP; ++j) m = fmaxf(m, fmaxf(aeven[j], aodd[j]));
    m = fmaxf(m, dppmov<0x111>(m));   // row_shr:1
    m = fmaxf(m, dppmov<0x112>(m));   // row_shr:2
    m = fmaxf(m, dppmov<0x114>(m));   // row_shr:4
    m = fmaxf(m, dppmov<0x118>(m));   // row_shr:8
    m = fmaxf(m, dppmov<0x142>(m));   // row_bcast:15
    m = fmaxf(m, dppmov<0x143>(m));   // row_bcast:31 -> lane 63 holds wave max
    const float wm  = __int_as_float(__builtin_amdgcn_readlane(__float_as_int(m), 63));
    const float inv = 1.0f / wm;
    lognorm += __logf(wm) - LOGM0f;
#pragma unroll
    for (int j = 0; j < PP; ++j) {
        aeven[j] = (aeven[j] * inv) * M0f;      // two-multiply: cannot overflow
        aodd[j]  = (aodd[j]  * inv) * M0f;
    }
}

template <int PP>
__device__ __forceinline__ void ctc_run(const float* __restrict__ Lb, float lsum,
                                        int tl, int ml, float* __restrict__ loss_out) {
    const int lane = threadIdx.x;
    const int base = lane * PP;

    // per-j clamped column offsets (clamped cols are always masked: k>=C >= tl)
    int   idx[PP];
    float mask[PP];
#pragma unroll
    for (int j = 0; j < PP; ++j) {
        const int k = base + j;
        idx[j]  = (k < C_) ? k : (C_ - 1);
        mask[j] = (k < tl) ? 1.f : 0.f;
    }

    // rotating 8-deep register row buffers; prologue loads rows 1..8 (ml >= 1024)
    float raw[8][PP];
#pragma unroll
    for (int s = 0; s < 8; ++s) {
        const float* __restrict__ rowp = Lb + (size_t)(s + 1) * C_;
#pragma unroll
        for (int j = 0; j < PP; ++j) raw[s][j] = rowp[idx[j]];
    }

    float aeven[PP], aodd[PP];
#pragma unroll
    for (int j = 0; j < PP; ++j) { aeven[j] = 0.f; aodd[j] = 0.f; }
    {
        const float a00 = __expf(Lb[0]) * M0f;   // raw-domain init, pre-scaled by M0
        if (lane == 0) { aeven[0] = a00; aodd[0] = a00; }
    }
    float lognorm = -LOGM0f;

    int tb = 1;
    for (; tb + 8 <= ml; tb += 8) {
#pragma unroll
        for (int s = 0; s < 8; ++s) {
            const int tt = tb + s;
            // consume row tt (loaded 8 steps ago): exp stage
            const float p0 = __expf(bcast0(raw[s][0]));   // column 0 = lane0's elem 0
            float p[PP];
#pragma unroll
            for (int j = 0; j < PP; ++j) p[j] = __expf(raw[s][j]) * mask[j];
            // reload row tt+8 into this slot (clamped; rows past ml-1 never consumed)
            {
                int tr = tt + 8; if (tr > ml - 1) tr = ml - 1;
                const float* __restrict__ rowp = Lb + (size_t)tr * C_;
#pragma unroll
                for (int j = 0; j < PP; ++j) raw[s][j] = rowp[idx[j]];
            }
            step_update<PP>(p0, p, aeven, aodd);
            if (s == 7) renorm<PP>(aeven, aodd, lognorm);   // tt = tb+7 == 0 (mod 8)
        }
    }
    // tail: rows tb..ml-1 (<8) already resident in slots 0.. (unclamped by construction)
#pragma unroll
    for (int s = 0; s < 8; ++s) {
        const int tt = tb + s;
        if (tt < ml) {
            const float p0 = __expf(bcast0(raw[s][0]));
            float p[PP];
#pragma unroll
            for (int j = 0; j < PP; ++j) p[j] = __expf(raw[s][j]) * mask[j];
            step_update<PP>(p0, p, aeven, aodd);
        }
    }

    // epilogue: ll = ln(alpha_raw[2tl] + alpha_raw[2tl-1]) + lognorm - lsum
    float contrib = 0.f;
#pragma unroll
    for (int j = 0; j < PP; ++j) {
        const int k = base + j;
        if (k == tl)     contrib += aeven[j];
        if (k == tl - 1) contrib += aodd[j];
    }
#pragma unroll
    for (int off = 32; off; off >>= 1) contrib += __shfl_xor(contrib, off);
    if (lane == 0) {
        float loss = 0.f;
        if (contrib > 0.f) {
            const float ll = __logf(contrib) + lognorm - lsum;
            loss = -ll / (float)tl;
        }
        *loss_out = loss;
    }
}

__global__ __launch_bounds__(64) void k_ctc(const float* __restrict__ logits,
                                            const int* __restrict__ text_lens,
                                            const int* __restrict__ mel_lens,
                                            const float* __restrict__ lsums,
                                            float* __restrict__ losses) {
    const int b  = blockIdx.x;
    const int tl = text_lens[b];
    const int ml = mel_lens[b];
    const float lsum = lsums[b];
    const float* Lb = logits + (size_t)b * T_ * C_;
    float* lo = losses + b;
    const int PP = (tl + 1 + 63) >> 6;   // pairs = tl+1, per-lane slots (2..7 here)
    switch (PP) {
        case 1: ctc_run<1>(Lb, lsum, tl, ml, lo); break;
        case 2: ctc_run<2>(Lb, lsum, tl, ml, lo); break;
        case 3: ctc_run<3>(Lb, lsum, tl, ml, lo); break;
        case 4: ctc_run<4>(Lb, lsum, tl, ml, lo); break;
        case 5: ctc_run<5>(Lb, lsum, tl, ml, lo); break;
        case 6: ctc_run<6>(Lb, lsum, tl, ml, lo); break;
        default: ctc_run<7>(Lb, lsum, tl, ml, lo); break;
    }
}

// ---------------- Pass C: deterministic mean ----------------
__global__ __launch_bounds__(64) void k_final(const float* __restrict__ losses,
                                              float* __restrict__ out) {
    const int lane = threadIdx.x;
    float v = (lane < B_) ? losses[lane] : 0.f;
#pragma unroll
    for (int off = 32; off; off >>= 1) v += __shfl_xor(v, off);
    if (lane == 0) out[0] = v * (1.0f / B_);
}

extern "C" void kernel_launch(void* const* d_in, const int* in_sizes, int n_in,
                              void* d_out, int out_size, void* d_ws, size_t ws_size,
                              hipStream_t stream) {
    const float* logits    = (const float*)d_in[0];   // [B,1,T,C] fp32
    const int*   text_lens = (const int*)d_in[1];     // [B] int32
    const int*   mel_lens  = (const int*)d_in[2];     // [B] int32
    float* ls     = (float*)d_ws;                     // B*T floats (256 KB)
    float* losses = ls + (size_t)B_ * T_;             // B floats
    float* lsums  = losses + B_;                      // B floats
    float* out    = (float*)d_out;

    k_rowstats<<<B_ * T_ / 4, 256, 0, stream>>>(logits, text_lens, ls);
    k_lsum<<<B_, 256, 0, stream>>>(ls, mel_lens, lsums);
    k_ctc<<<B_, 64, 0, stream>>>(logits, text_lens, mel_lens, lsums, losses);
    k_final<<<1, 64, 0, stream>>>(losses, out);
}

// Round 6
// 243.347 us; speedup vs baseline: 4.2585x; 1.4046x over previous
//
#include <hip/hip_runtime.h>

// ForwardSumLossWithBlank: CTC forward (alpha) loss, blank=0, targets=arange(text_len).
// B=32, T=2000 mel frames, C=400 classes. Output: scalar mean loss (fp32).
//
// FAST path (needs ~66 MB of d_ws):
//   Pass A  (k_prob): per row, masked NORMALIZED probs -> bf16 padded [T][512] in ws,
//           plus ls[b,t] = ln(sum exp) (used only by fallback). exp/mask/normalize all
//           hoisted out of pass B. NOTE: probs are normalized, so pass B must NOT
//           subtract the log-denominator again (R5 bug: double-subtraction, absmax 45).
//   Pass B  (k_ctc_fast): one wave per sample, uniform 8 pairs/lane. Per step:
//           ONE global_load_dwordx4 (8 bf16), 8 shift/and converts, 32-op banded
//           recurrence update, 1 DPP for the cross-lane neighbor; renorm every 8
//           steps via DPP max-reduce. 16-deep rotating register ring hides latency.
//   Pass C  (k_final): deterministic mean.
// FALLBACK path (small ws): proven R4 kernels (raw exp(logits) loads, -lsum epilogue).

static constexpr int B_ = 32;
static constexpr int T_ = 2000;
static constexpr int C_ = 400;
static constexpr float M0f    = 1e20f;
static constexpr float LOGM0f = 46.05170186f;   // ln(1e20)

template <int CTRL>
__device__ __forceinline__ float dppmov(float v) {
    // mov_dpp, bound_ctrl=1: invalid-source lanes read 0 (safe: alphas >= 0).
    return __int_as_float(__builtin_amdgcn_update_dpp(
        0, __float_as_int(v), CTRL, 0xF, 0xF, true));
}

__device__ __forceinline__ float bcast0(float v) {
    return __int_as_float(__builtin_amdgcn_readfirstlane(__float_as_int(v)));
}

__device__ __forceinline__ unsigned bf16rne(float f) {
    unsigned u = __float_as_uint(f);
    u += 0x7FFFu + ((u >> 16) & 1u);
    return u >> 16;
}

// ---------------- Pass A: masked normalized probs (bf16, padded 512) + ln-sum ----------------
__global__ __launch_bounds__(256) void k_prob(const float* __restrict__ logits,
                                              const int* __restrict__ text_lens,
                                              unsigned short* __restrict__ pbf,  // may be null
                                              float* __restrict__ ls) {
    const int lane = threadIdx.x & 63;
    const int row  = blockIdx.x * 4 + (threadIdx.x >> 6);   // grid = B*T/4 exactly
    const int b    = row / T_;
    const int tl   = text_lens[b];
    const float* __restrict__ r = logits + (size_t)row * C_;

    const int c0 = lane * 8;
    float v[8];
    if (c0 < C_) {           // row is 1600 B, 16B-aligned; lane<50 reads [c0, c0+8)
        const float4 a = *(const float4*)(r + c0);
        const float4 c = *(const float4*)(r + c0 + 4);
        v[0]=a.x; v[1]=a.y; v[2]=a.z; v[3]=a.w; v[4]=c.x; v[5]=c.y; v[6]=c.z; v[7]=c.w;
    } else {
#pragma unroll
        for (int e = 0; e < 8; ++e) v[e] = 0.f;             // masked below anyway
    }
    float ex[8]; float s = 0.f;
#pragma unroll
    for (int e = 0; e < 8; ++e) {
        const int c = c0 + e;
        const float t = (c < tl) ? __expf(v[e]) : 0.f;      // tl <= 400 -> cols>=400 masked
        ex[e] = t; s += t;
    }
#pragma unroll
    for (int off = 32; off; off >>= 1) s += __shfl_xor(s, off);

    if (pbf) {
        const float inv = 1.0f / s;
        uint4 st;
        st.x = bf16rne(ex[0]*inv) | (bf16rne(ex[1]*inv) << 16);
        st.y = bf16rne(ex[2]*inv) | (bf16rne(ex[3]*inv) << 16);
        st.z = bf16rne(ex[4]*inv) | (bf16rne(ex[5]*inv) << 16);
        st.w = bf16rne(ex[6]*inv) | (bf16rne(ex[7]*inv) << 16);
        *(uint4*)(pbf + (size_t)row * 512 + c0) = st;       // coalesced 1 KB/wave
    }
    if (lane == 0) ls[row] = __logf(s);
}

// ---------------- Pass A2 (fallback only): per-sample sum of ln-denominators ----------------
__global__ __launch_bounds__(256) void k_lsum(const float* __restrict__ ls,
                                              const int* __restrict__ mel_lens,
                                              float* __restrict__ lsums) {
    const int b  = blockIdx.x;
    const int ml = mel_lens[b];
    float s = 0.f;
    for (int i = threadIdx.x; i < ml; i += 256) s += ls[(size_t)b * T_ + i];
#pragma unroll
    for (int off = 32; off; off >>= 1) s += __shfl_xor(s, off);
    __shared__ float ws[4];
    if ((threadIdx.x & 63) == 0) ws[threadIdx.x >> 6] = s;
    __syncthreads();
    if (threadIdx.x == 0) lsums[b] = (ws[0] + ws[1]) + (ws[2] + ws[3]);
}

// ---------------- shared recursion pieces ----------------
// Pair k holds states (2k, 2k+1); pair tl holds only the final even state 2*tl.
//   e = a[2k] + a[2k-1];  a'[2k] = e*p0;  a'[2k+1] = (a[2k+1]+e)*pk
template <int PP>
__device__ __forceinline__ void step_update(const float p0, const float* __restrict__ p,
                                            float* __restrict__ aeven, float* __restrict__ aodd) {
    float prev = dppmov<0x138>(aodd[PP - 1]);   // wave_shr:1; lane0 reads 0
#pragma unroll
    for (int j = 0; j < PP; ++j) {
        const float oldodd = aodd[j];
        const float e = aeven[j] + prev;
        aeven[j] = e * p0;
        aodd[j]  = (oldodd + e) * p[j];
        prev = oldodd;
    }
}

template <int PP>
__device__ __forceinline__ void renorm(float* __restrict__ aeven, float* __restrict__ aodd,
                                       float& lognorm) {
    float m = 0.f;
#pragma unroll
    for (int j = 0; j < PP; ++j) m = fmaxf(m, fmaxf(aeven[j], aodd[j]));
    m = fmaxf(m, dppmov<0x111>(m));   // row_shr:1
    m = fmaxf(m, dppmov<0x112>(m));   // row_shr:2
    m = fmaxf(m, dppmov<0x114>(m));   // row_shr:4
    m = fmaxf(m, dppmov<0x118>(m));   // row_shr:8
    m = fmaxf(m, dppmov<0x142>(m));   // row_bcast:15
    m = fmaxf(m, dppmov<0x143>(m));   // row_bcast:31 -> lane 63 holds wave max
    const float wm  = __int_as_float(__builtin_amdgcn_readlane(__float_as_int(m), 63));
    const float inv = 1.0f / wm;
    lognorm += __logf(wm) - LOGM0f;
#pragma unroll
    for (int j = 0; j < PP; ++j) {
        aeven[j] = (aeven[j] * inv) * M0f;      // two-multiply: cannot overflow
        aodd[j]  = (aodd[j]  * inv) * M0f;
    }
}

// ---------------- Pass B (fast): bf16 normalized probs, uniform 8 pairs/lane ----------------
__global__ __launch_bounds__(64) void k_ctc_fast(const unsigned short* __restrict__ pbf,
                                                 const int* __restrict__ text_lens,
                                                 const int* __restrict__ mel_lens,
                                                 float* __restrict__ losses) {
    const int b    = blockIdx.x;
    const int lane = threadIdx.x;
    const int tl   = text_lens[b];
    const int ml   = mel_lens[b];
    const unsigned short* __restrict__ pb = pbf + (size_t)b * T_ * 512;
    const uint4* __restrict__ base = (const uint4*)pb;       // 64 uint4 per row

    // 16-deep rotating register ring; prologue loads rows 1..16 (ml >= 1024)
    uint4 raw[16];
#pragma unroll
    for (int s = 0; s < 16; ++s) raw[s] = base[(size_t)(s + 1) * 64 + lane];

    float aeven[8], aodd[8];
#pragma unroll
    for (int j = 0; j < 8; ++j) { aeven[j] = 0.f; aodd[j] = 0.f; }
    {   // alpha0[0] = alpha0[1] = p(t=0, class 0), pre-scaled by M0
        const float p00 = __uint_as_float(((unsigned)pb[0]) << 16) * M0f;
        if (lane == 0) { aeven[0] = p00; aodd[0] = p00; }
    }
    float lognorm = -LOGM0f;

#define CONSUME(S)                                                                 \
    {                                                                              \
        const uint4 w = raw[S];                                                    \
        const unsigned p0b = (unsigned)__builtin_amdgcn_readfirstlane((int)w.x);   \
        const float p0 = __uint_as_float(p0b << 16);                               \
        float p[8];                                                                \
        p[0] = __uint_as_float(w.x << 16); p[1] = __uint_as_float(w.x & 0xFFFF0000u); \
        p[2] = __uint_as_float(w.y << 16); p[3] = __uint_as_float(w.y & 0xFFFF0000u); \
        p[4] = __uint_as_float(w.z << 16); p[5] = __uint_as_float(w.z & 0xFFFF0000u); \
        p[6] = __uint_as_float(w.w << 16); p[7] = __uint_as_float(w.w & 0xFFFF0000u); \
        step_update<8>(p0, p, aeven, aodd);                                        \
    }

    int tb = 1;
    for (; tb + 16 <= ml; tb += 16) {
#pragma unroll
        for (int s = 0; s < 16; ++s) {
            const int tt = tb + s;
            const uint4 w = raw[s];
            const unsigned p0b = (unsigned)__builtin_amdgcn_readfirstlane((int)w.x);
            const float p0 = __uint_as_float(p0b << 16);
            float p[8];
            p[0] = __uint_as_float(w.x << 16); p[1] = __uint_as_float(w.x & 0xFFFF0000u);
            p[2] = __uint_as_float(w.y << 16); p[3] = __uint_as_float(w.y & 0xFFFF0000u);
            p[4] = __uint_as_float(w.z << 16); p[5] = __uint_as_float(w.z & 0xFFFF0000u);
            p[6] = __uint_as_float(w.w << 16); p[7] = __uint_as_float(w.w & 0xFFFF0000u);
            // reload row tt+16 into this slot (clamped rows are never consumed)
            { int tr = tt + 16; if (tr > ml - 1) tr = ml - 1;
              raw[s] = base[(size_t)tr * 64 + lane]; }
            step_update<8>(p0, p, aeven, aodd);
            if ((s & 7) == 7) renorm<8>(aeven, aodd, lognorm);   // tt%8==0 positions
        }
    }
    // tail: rows tb..ml-1 (<16) already resident, unclamped by construction
#pragma unroll
    for (int s = 0; s < 16; ++s) {
        const int tt = tb + s;
        if (tt < ml) {
            CONSUME(s)
            if ((s & 7) == 7) renorm<8>(aeven, aodd, lognorm);
        }
    }
#undef CONSUME

    // epilogue: probs are already normalized -> ll = ln(contrib) + lognorm (NO -lsum)
    float contrib = 0.f;
#pragma unroll
    for (int j = 0; j < 8; ++j) {
        const int k = lane * 8 + j;
        if (k == tl)     contrib += aeven[j];
        if (k == tl - 1) contrib += aodd[j];
    }
#pragma unroll
    for (int off = 32; off; off >>= 1) contrib += __shfl_xor(contrib, off);
    if (lane == 0) {
        float loss = 0.f;
        if (contrib > 0.f) {
            const float ll = __logf(contrib) + lognorm;
            loss = -ll / (float)tl;
        }
        losses[b] = loss;
    }
}

// ---------------- Pass B (fallback, proven R4): direct logit loads ----------------
template <int PP>
__device__ __forceinline__ void ctc_run_slow(const float* __restrict__ Lb, float lsum,
                                             int tl, int ml, float* __restrict__ loss_out) {
    const int lane = threadIdx.x;
    const int base = lane * PP;
    int   idx[PP];
    float mask[PP];
#pragma unroll
    for (int j = 0; j < PP; ++j) {
        const int k = base + j;
        idx[j]  = (k < C_) ? k : (C_ - 1);
        mask[j] = (k < tl) ? 1.f : 0.f;
    }
    float raw[8][PP];
#pragma unroll
    for (int s = 0; s < 8; ++s) {
        const float* __restrict__ rowp = Lb + (size_t)(s + 1) * C_;
#pragma unroll
        for (int j = 0; j < PP; ++j) raw[s][j] = rowp[idx[j]];
    }
    float aeven[PP], aodd[PP];
#pragma unroll
    for (int j = 0; j < PP; ++j) { aeven[j] = 0.f; aodd[j] = 0.f; }
    {
        const float a00 = __expf(Lb[0]) * M0f;
        if (lane == 0) { aeven[0] = a00; aodd[0] = a00; }
    }
    float lognorm = -LOGM0f;
    int tb = 1;
    for (; tb + 8 <= ml; tb += 8) {
#pragma unroll
        for (int s = 0; s < 8; ++s) {
            const int tt = tb + s;
            const float p0 = __expf(bcast0(raw[s][0]));
            float p[PP];
#pragma unroll
            for (int j = 0; j < PP; ++j) p[j] = __expf(raw[s][j]) * mask[j];
            { int tr = tt + 8; if (tr > ml - 1) tr = ml - 1;
              const float* __restrict__ rowp = Lb + (size_t)tr * C_;
#pragma unroll
              for (int j = 0; j < PP; ++j) raw[s][j] = rowp[idx[j]]; }
            step_update<PP>(p0, p, aeven, aodd);
            if (s == 7) renorm<PP>(aeven, aodd, lognorm);
        }
    }
#pragma unroll
    for (int s = 0; s < 8; ++s) {
        const int tt = tb + s;
        if (tt < ml) {
            const float p0 = __expf(bcast0(raw[s][0]));
            float p[PP];
#pragma unroll
            for (int j = 0; j < PP; ++j) p[j] = __expf(raw[s][j]) * mask[j];
            step_update<PP>(p0, p, aeven, aodd);
            if (s == 7) renorm<PP>(aeven, aodd, lognorm);
        }
    }
    float contrib = 0.f;
#pragma unroll
    for (int j = 0; j < PP; ++j) {
        const int k = base + j;
        if (k == tl)     contrib += aeven[j];
        if (k == tl - 1) contrib += aodd[j];
    }
#pragma unroll
    for (int off = 32; off; off >>= 1) contrib += __shfl_xor(contrib, off);
    if (lane == 0) {
        float loss = 0.f;
        if (contrib > 0.f) {
            const float ll = __logf(contrib) + lognorm - lsum;   // raw domain: -lsum needed
            loss = -ll / (float)tl;
        }
        *loss_out = loss;
    }
}

__global__ __launch_bounds__(64) void k_ctc_slow(const float* __restrict__ logits,
                                                 const int* __restrict__ text_lens,
                                                 const int* __restrict__ mel_lens,
                                                 const float* __restrict__ lsums,
                                                 float* __restrict__ losses) {
    const int b  = blockIdx.x;
    const int tl = text_lens[b];
    const int ml = mel_lens[b];
    const float lsum = lsums[b];
    const float* Lb = logits + (size_t)b * T_ * C_;
    float* lo = losses + b;
    const int PP = (tl + 1 + 63) >> 6;
    switch (PP) {
        case 1: ctc_run_slow<1>(Lb, lsum, tl, ml, lo); break;
        case 2: ctc_run_slow<2>(Lb, lsum, tl, ml, lo); break;
        case 3: ctc_run_slow<3>(Lb, lsum, tl, ml, lo); break;
        case 4: ctc_run_slow<4>(Lb, lsum, tl, ml, lo); break;
        case 5: ctc_run_slow<5>(Lb, lsum, tl, ml, lo); break;
        case 6: ctc_run_slow<6>(Lb, lsum, tl, ml, lo); break;
        default: ctc_run_slow<7>(Lb, lsum, tl, ml, lo); break;
    }
}

// ---------------- Pass C: deterministic mean ----------------
__global__ __launch_bounds__(64) void k_final(const float* __restrict__ losses,
                                              float* __restrict__ out) {
    const int lane = threadIdx.x;
    float v = (lane < B_) ? losses[lane] : 0.f;
#pragma unroll
    for (int off = 32; off; off >>= 1) v += __shfl_xor(v, off);
    if (lane == 0) out[0] = v * (1.0f / B_);
}

extern "C" void kernel_launch(void* const* d_in, const int* in_sizes, int n_in,
                              void* d_out, int out_size, void* d_ws, size_t ws_size,
                              hipStream_t stream) {
    const float* logits    = (const float*)d_in[0];   // [B,1,T,C] fp32
    const int*   text_lens = (const int*)d_in[1];     // [B] int32
    const int*   mel_lens  = (const int*)d_in[2];     // [B] int32
    float* out = (float*)d_out;

    const size_t PBF_BYTES = (size_t)B_ * T_ * 512 * 2;           // 65,536,000
    const size_t need = PBF_BYTES + (size_t)B_ * T_ * 4 + 2 * B_ * 4 + 64;

    if (ws_size >= need) {
        unsigned short* pbf = (unsigned short*)d_ws;
        float* ls     = (float*)((char*)d_ws + PBF_BYTES);
        float* lsums  = ls + (size_t)B_ * T_;
        float* losses = lsums + B_;
        k_prob<<<B_ * T_ / 4, 256, 0, stream>>>(logits, text_lens, pbf, ls);
        k_ctc_fast<<<B_, 64, 0, stream>>>(pbf, text_lens, mel_lens, losses);
        k_final<<<1, 64, 0, stream>>>(losses, out);
    } else {
        float* ls     = (float*)d_ws;
        float* lsums  = ls + (size_t)B_ * T_;
        float* losses = lsums + B_;
        k_prob<<<B_ * T_ / 4, 256, 0, stream>>>(logits, text_lens, nullptr, ls);
        k_lsum<<<B_, 256, 0, stream>>>(ls, mel_lens, lsums);
        k_ctc_slow<<<B_, 64, 0, stream>>>(logits, text_lens, mel_lens, lsums, losses);
        k_final<<<1, 64, 0, stream>>>(losses, out);
    }
}

// Round 8
// 229.632 us; speedup vs baseline: 4.5129x; 1.0597x over previous
//
#include <hip/hip_runtime.h>

// ForwardSumLossWithBlank: CTC forward (alpha) loss, blank=0, targets=arange(text_len).
// B=32, T=2000 mel frames, C=400 classes. Output: scalar mean loss (fp32).
//
// FAST path (needs ~66 MB of d_ws):
//   Pass A (k_prob): masked NORMALIZED probs -> bf16 padded [T][512] in ws (+ ls for
//          the fallback). All exp/mask/normalize hoisted out of the serial pass.
//   Pass B (k_ctc_fast): one wave per sample, uniform 8 pairs/lane. Per step: ONE
//          global_load_dwordx4 (16-deep ring), bf16 converts + p0 readfirstlane
//          PIPELINED ONE STEP AHEAD (pA/pB, bit-exact), 32-op banded update, 1 DPP
//          neighbor. Renorm every 8 steps, FRESH (R7's 7-step-stale apply raised the
//          fp32 flush floor ~18 nats -> +2ULP error; reverted), exponent-only:
//          exact pow2 scale pins post-apply max in [2^66,2^67), integer lognorm,
//          no rcp/log in the loop.
//   Pass C (k_final): deterministic mean.
// FALLBACK path (small ws): proven R4 kernels (raw exp(logits), -lsum epilogue).

static constexpr int B_ = 32;
static constexpr int T_ = 2000;
static constexpr int C_ = 400;
static constexpr float M0f    = 1e20f;
static constexpr float LOGM0f = 46.05170186f;   // ln(1e20) (fallback path)

template <int CTRL>
__device__ __forceinline__ float dppmov(float v) {
    // mov_dpp, bound_ctrl=1: invalid-source lanes read 0 (safe: alphas >= 0).
    return __int_as_float(__builtin_amdgcn_update_dpp(
        0, __float_as_int(v), CTRL, 0xF, 0xF, true));
}

__device__ __forceinline__ float bcast0(float v) {
    return __int_as_float(__builtin_amdgcn_readfirstlane(__float_as_int(v)));
}

__device__ __forceinline__ unsigned bf16rne(float f) {
    unsigned u = __float_as_uint(f);
    u += 0x7FFFu + ((u >> 16) & 1u);
    return u >> 16;
}

// ---------------- Pass A: masked normalized probs (bf16, padded 512) + ln-sum ----------------
__global__ __launch_bounds__(256) void k_prob(const float* __restrict__ logits,
                                              const int* __restrict__ text_lens,
                                              unsigned short* __restrict__ pbf,  // may be null
                                              float* __restrict__ ls) {
    const int lane = threadIdx.x & 63;
    const int row  = blockIdx.x * 4 + (threadIdx.x >> 6);   // grid = B*T/4 exactly
    const int b    = row / T_;
    const int tl   = text_lens[b];
    const float* __restrict__ r = logits + (size_t)row * C_;

    const int c0 = lane * 8;
    float v[8];
    if (c0 < C_) {           // row is 1600 B, 16B-aligned; lane<50 reads [c0, c0+8)
        const float4 a = *(const float4*)(r + c0);
        const float4 c = *(const float4*)(r + c0 + 4);
        v[0]=a.x; v[1]=a.y; v[2]=a.z; v[3]=a.w; v[4]=c.x; v[5]=c.y; v[6]=c.z; v[7]=c.w;
    } else {
#pragma unroll
        for (int e = 0; e < 8; ++e) v[e] = 0.f;             // masked below anyway
    }
    float ex[8]; float s = 0.f;
#pragma unroll
    for (int e = 0; e < 8; ++e) {
        const int c = c0 + e;
        const float t = (c < tl) ? __expf(v[e]) : 0.f;      // tl <= 400 -> cols>=400 masked
        ex[e] = t; s += t;
    }
#pragma unroll
    for (int off = 32; off; off >>= 1) s += __shfl_xor(s, off);

    if (pbf) {
        const float inv = 1.0f / s;
        uint4 st;
        st.x = bf16rne(ex[0]*inv) | (bf16rne(ex[1]*inv) << 16);
        st.y = bf16rne(ex[2]*inv) | (bf16rne(ex[3]*inv) << 16);
        st.z = bf16rne(ex[4]*inv) | (bf16rne(ex[5]*inv) << 16);
        st.w = bf16rne(ex[6]*inv) | (bf16rne(ex[7]*inv) << 16);
        *(uint4*)(pbf + (size_t)row * 512 + c0) = st;       // coalesced 1 KB/wave
    }
    if (lane == 0) ls[row] = __logf(s);
}

// ---------------- Pass A2 (fallback only): per-sample sum of ln-denominators ----------------
__global__ __launch_bounds__(256) void k_lsum(const float* __restrict__ ls,
                                              const int* __restrict__ mel_lens,
                                              float* __restrict__ lsums) {
    const int b  = blockIdx.x;
    const int ml = mel_lens[b];
    float s = 0.f;
    for (int i = threadIdx.x; i < ml; i += 256) s += ls[(size_t)b * T_ + i];
#pragma unroll
    for (int off = 32; off; off >>= 1) s += __shfl_xor(s, off);
    __shared__ float ws[4];
    if ((threadIdx.x & 63) == 0) ws[threadIdx.x >> 6] = s;
    __syncthreads();
    if (threadIdx.x == 0) lsums[b] = (ws[0] + ws[1]) + (ws[2] + ws[3]);
}

// ---------------- shared recursion pieces ----------------
// Pair k holds states (2k, 2k+1); pair tl holds only the final even state 2*tl.
//   e = a[2k] + a[2k-1];  a'[2k] = e*p0;  a'[2k+1] = (a[2k+1]+e)*pk
template <int PP>
__device__ __forceinline__ void step_update(const float p0, const float* __restrict__ p,
                                            float* __restrict__ aeven, float* __restrict__ aodd) {
    float prev = dppmov<0x138>(aodd[PP - 1]);   // wave_shr:1; lane0 reads 0
#pragma unroll
    for (int j = 0; j < PP; ++j) {
        const float oldodd = aodd[j];
        const float e = aeven[j] + prev;
        aeven[j] = e * p0;
        aodd[j]  = (oldodd + e) * p[j];
        prev = oldodd;
    }
}

// FRESH exponent-only renorm: wave max via local max3 tree + 6 DPP levels + readlane,
// scale = exact 2^(66-ex) (pins post-apply max in [2^66,2^67)), integer lognorm.
__device__ __forceinline__ void renorm_exp(float* __restrict__ aeven,
                                           float* __restrict__ aodd, int& exacc) {
    const float q0 = fmaxf(aeven[0], aodd[0]);
    const float q1 = fmaxf(aeven[1], aodd[1]);
    const float q2 = fmaxf(aeven[2], aodd[2]);
    const float q3 = fmaxf(aeven[3], aodd[3]);
    const float q4 = fmaxf(aeven[4], aodd[4]);
    const float q5 = fmaxf(aeven[5], aodd[5]);
    const float q6 = fmaxf(aeven[6], aodd[6]);
    const float q7 = fmaxf(aeven[7], aodd[7]);
    float m = fmaxf(fmaxf(fmaxf(q0, q1), q2),
                    fmaxf(fmaxf(fmaxf(q3, q4), q5), fmaxf(q6, q7)));
    m = fmaxf(m, dppmov<0x111>(m));   // row_shr:1
    m = fmaxf(m, dppmov<0x112>(m));   // row_shr:2
    m = fmaxf(m, dppmov<0x114>(m));   // row_shr:4
    m = fmaxf(m, dppmov<0x118>(m));   // row_shr:8
    m = fmaxf(m, dppmov<0x142>(m));   // row_bcast:15
    m = fmaxf(m, dppmov<0x143>(m));   // row_bcast:31 -> lane 63 holds wave max
    const int wmb = __builtin_amdgcn_readlane(__float_as_int(m), 63);
    int ex = ((wmb >> 23) & 0xFF) - 127;
    if (ex < -60) ex = -60;                 // guard vs denorm/zero max
    exacc += ex - 66;
    const float scale = __int_as_float((unsigned)(193 - ex) << 23);  // 2^(66-ex), exact
#pragma unroll
    for (int j = 0; j < 8; ++j) { aeven[j] *= scale; aodd[j] *= scale; }
}

// old single-shot renorm (fallback path only)
template <int PP>
__device__ __forceinline__ void renorm(float* __restrict__ aeven, float* __restrict__ aodd,
                                       float& lognorm) {
    float m = 0.f;
#pragma unroll
    for (int j = 0; j < PP; ++j) m = fmaxf(m, fmaxf(aeven[j], aodd[j]));
    m = fmaxf(m, dppmov<0x111>(m));
    m = fmaxf(m, dppmov<0x112>(m));
    m = fmaxf(m, dppmov<0x114>(m));
    m = fmaxf(m, dppmov<0x118>(m));
    m = fmaxf(m, dppmov<0x142>(m));
    m = fmaxf(m, dppmov<0x143>(m));
    const float wm  = __int_as_float(__builtin_amdgcn_readlane(__float_as_int(m), 63));
    const float inv = 1.0f / wm;
    lognorm += __logf(wm) - LOGM0f;
#pragma unroll
    for (int j = 0; j < PP; ++j) {
        aeven[j] = (aeven[j] * inv) * M0f;
        aodd[j]  = (aodd[j]  * inv) * M0f;
    }
}

// ---------------- Pass B (fast): bf16 normalized probs, uniform 8 pairs/lane ----------------
__global__ __launch_bounds__(64) void k_ctc_fast(const unsigned short* __restrict__ pbf,
                                                 const int* __restrict__ text_lens,
                                                 const int* __restrict__ mel_lens,
                                                 float* __restrict__ losses) {
    const int b    = blockIdx.x;
    const int lane = threadIdx.x;
    const int tl   = text_lens[b];
    const int ml   = mel_lens[b];
    const unsigned short* __restrict__ pb = pbf + (size_t)b * T_ * 512;
    const uint4* __restrict__ base = (const uint4*)pb;       // 64 uint4 per row

    // 16-deep rotating register ring; prologue loads rows 1..16 (ml >= 1024)
    uint4 raw[16];
#pragma unroll
    for (int s = 0; s < 16; ++s) raw[s] = base[(size_t)(s + 1) * 64 + lane];

    float aeven[8], aodd[8];
#pragma unroll
    for (int j = 0; j < 8; ++j) { aeven[j] = 0.f; aodd[j] = 0.f; }
    {   // alpha0[0] = alpha0[1] = p(t=0, class 0), pre-scaled by 2^66
        const float p00 = __uint_as_float(((unsigned)pb[0]) << 16) * 0x1p66f;
        if (lane == 0) { aeven[0] = p00; aodd[0] = p00; }
    }
    int exacc = -66;                  // lognorm = exacc * ln2 at the end

#define CVT8(SLOT, P, P0)  { const uint4 w = raw[SLOT];                                     \
        P0 = __uint_as_float(((unsigned)__builtin_amdgcn_readfirstlane((int)w.x)) << 16);   \
        P[0]=__uint_as_float(w.x<<16); P[1]=__uint_as_float(w.x&0xFFFF0000u);               \
        P[2]=__uint_as_float(w.y<<16); P[3]=__uint_as_float(w.y&0xFFFF0000u);               \
        P[4]=__uint_as_float(w.z<<16); P[5]=__uint_as_float(w.z&0xFFFF0000u);               \
        P[6]=__uint_as_float(w.w<<16); P[7]=__uint_as_float(w.w&0xFFFF0000u); }

    float pA[8], pB[8], p0A, p0B;
    CVT8(0, pA, p0A)                  // row 1 (= first consumed row)

    // main loop: consume row tb+S from its p-buffer (converted one step earlier),
    // reload slot S with row tb+S+16, convert slot S+1 for the next step.
    // CLAMPED=0 steady state has tr = tb+S+16 <= tb+31 <= ml-1 by loop bound.
#define STEP_MAIN(S, PIN, P0IN, POUT, P0OUT, CLAMPED)                          \
    { int tr = tb + (S) + 16;                                                  \
      if (CLAMPED) { if (tr > ml - 1) tr = ml - 1; }                           \
      raw[S] = base[(size_t)tr * 64 + lane]; }                                 \
    CVT8(((S) + 1) & 15, POUT, P0OUT)                                          \
    step_update<8>(P0IN, PIN, aeven, aodd);                                    \
    if (((S) & 7) == 7) renorm_exp(aeven, aodd, exacc);

#define BLOCK16(CLAMPED)                                                       \
        STEP_MAIN(0,  pA, p0A, pB, p0B, CLAMPED)                               \
        STEP_MAIN(1,  pB, p0B, pA, p0A, CLAMPED)                               \
        STEP_MAIN(2,  pA, p0A, pB, p0B, CLAMPED)                               \
        STEP_MAIN(3,  pB, p0B, pA, p0A, CLAMPED)                               \
        STEP_MAIN(4,  pA, p0A, pB, p0B, CLAMPED)                               \
        STEP_MAIN(5,  pB, p0B, pA, p0A, CLAMPED)                               \
        STEP_MAIN(6,  pA, p0A, pB, p0B, CLAMPED)                               \
        STEP_MAIN(7,  pB, p0B, pA, p0A, CLAMPED)                               \
        STEP_MAIN(8,  pA, p0A, pB, p0B, CLAMPED)                               \
        STEP_MAIN(9,  pB, p0B, pA, p0A, CLAMPED)                               \
        STEP_MAIN(10, pA, p0A, pB, p0B, CLAMPED)                               \
        STEP_MAIN(11, pB, p0B, pA, p0A, CLAMPED)                               \
        STEP_MAIN(12, pA, p0A, pB, p0B, CLAMPED)                               \
        STEP_MAIN(13, pB, p0B, pA, p0A, CLAMPED)                               \
        STEP_MAIN(14, pA, p0A, pB, p0B, CLAMPED)                               \
        STEP_MAIN(15, pB, p0B, pA, p0A, CLAMPED)

    int tb = 1;
    for (; tb + 32 <= ml; tb += 16) {       // steady state: reloads never clamp
        BLOCK16(0)
    }
    if (tb + 16 <= ml) {                    // one transition block with clamps
        BLOCK16(1)
        tb += 16;
    }

    // tail: rows tb..ml-1 (<16) resident in slots 0.. ; no renorm (<=15 steps of
    // drift from the last apply stays comfortably inside fp32 range).
#define STEP_TAIL(S, PIN, P0IN, POUT, P0OUT)                                   \
    if (tb + (S) < ml) {                                                       \
        CVT8(((S) + 1) & 15, POUT, P0OUT)                                      \
        step_update<8>(P0IN, PIN, aeven, aodd);                                \
    }
    STEP_TAIL(0,  pA, p0A, pB, p0B)
    STEP_TAIL(1,  pB, p0B, pA, p0A)
    STEP_TAIL(2,  pA, p0A, pB, p0B)
    STEP_TAIL(3,  pB, p0B, pA, p0A)
    STEP_TAIL(4,  pA, p0A, pB, p0B)
    STEP_TAIL(5,  pB, p0B, pA, p0A)
    STEP_TAIL(6,  pA, p0A, pB, p0B)
    STEP_TAIL(7,  pB, p0B, pA, p0A)
    STEP_TAIL(8,  pA, p0A, pB, p0B)
    STEP_TAIL(9,  pB, p0B, pA, p0A)
    STEP_TAIL(10, pA, p0A, pB, p0B)
    STEP_TAIL(11, pB, p0B, pA, p0A)
    STEP_TAIL(12, pA, p0A, pB, p0B)
    STEP_TAIL(13, pB, p0B, pA, p0A)
    STEP_TAIL(14, pA, p0A, pB, p0B)
    STEP_TAIL(15, pB, p0B, pA, p0A)
#undef STEP_TAIL
#undef BLOCK16
#undef STEP_MAIN
#undef CVT8

    // epilogue: probs are normalized -> ll = ln(contrib) + exacc*ln2
    float contrib = 0.f;
#pragma unroll
    for (int j = 0; j < 8; ++j) {
        const int k = lane * 8 + j;
        if (k == tl)     contrib += aeven[j];
        if (k == tl - 1) contrib += aodd[j];
    }
#pragma unroll
    for (int off = 32; off; off >>= 1) contrib += __shfl_xor(contrib, off);
    if (lane == 0) {
        float loss = 0.f;
        if (contrib > 0.f) {
            const float ll = __logf(contrib) + (float)exacc * 0.69314718056f;
            loss = -ll / (float)tl;
        }
        losses[b] = loss;
    }
}

// ---------------- Pass B (fallback, proven R4): direct logit loads ----------------
template <int PP>
__device__ __forceinline__ void ctc_run_slow(const float* __restrict__ Lb, float lsum,
                                             int tl, int ml, float* __restrict__ loss_out) {
    const int lane = threadIdx.x;
    const int base = lane * PP;
    int   idx[PP];
    float mask[PP];
#pragma unroll
    for (int j = 0; j < PP; ++j) {
        const int k = base + j;
        idx[j]  = (k < C_) ? k : (C_ - 1);
        mask[j] = (k < tl) ? 1.f : 0.f;
    }
    float raw[8][PP];
#pragma unroll
    for (int s = 0; s < 8; ++s) {
        const float* __restrict__ rowp = Lb + (size_t)(s + 1) * C_;
#pragma unroll
        for (int j = 0; j < PP; ++j) raw[s][j] = rowp[idx[j]];
    }
    float aeven[PP], aodd[PP];
#pragma unroll
    for (int j = 0; j < PP; ++j) { aeven[j] = 0.f; aodd[j] = 0.f; }
    {
        const float a00 = __expf(Lb[0]) * M0f;
        if (lane == 0) { aeven[0] = a00; aodd[0] = a00; }
    }
    float lognorm = -LOGM0f;
    int tb = 1;
    for (; tb + 8 <= ml; tb += 8) {
#pragma unroll
        for (int s = 0; s < 8; ++s) {
            const int tt = tb + s;
            const float p0 = __expf(bcast0(raw[s][0]));
            float p[PP];
#pragma unroll
            for (int j = 0; j < PP; ++j) p[j] = __expf(raw[s][j]) * mask[j];
            { int tr = tt + 8; if (tr > ml - 1) tr = ml - 1;
              const float* __restrict__ rowp = Lb + (size_t)tr * C_;
#pragma unroll
              for (int j = 0; j < PP; ++j) raw[s][j] = rowp[idx[j]]; }
            step_update<PP>(p0, p, aeven, aodd);
            if (s == 7) renorm<PP>(aeven, aodd, lognorm);
        }
    }
#pragma unroll
    for (int s = 0; s < 8; ++s) {
        const int tt = tb + s;
        if (tt < ml) {
            const float p0 = __expf(bcast0(raw[s][0]));
            float p[PP];
#pragma unroll
            for (int j = 0; j < PP; ++j) p[j] = __expf(raw[s][j]) * mask[j];
            step_update<PP>(p0, p, aeven, aodd);
            if (s == 7) renorm<PP>(aeven, aodd, lognorm);
        }
    }
    float contrib = 0.f;
#pragma unroll
    for (int j = 0; j < PP; ++j) {
        const int k = base + j;
        if (k == tl)     contrib += aeven[j];
        if (k == tl - 1) contrib += aodd[j];
    }
#pragma unroll
    for (int off = 32; off; off >>= 1) contrib += __shfl_xor(contrib, off);
    if (lane == 0) {
        float loss = 0.f;
        if (contrib > 0.f) {
            const float ll = __logf(contrib) + lognorm - lsum;   // raw domain: -lsum needed
            loss = -ll / (float)tl;
        }
        *loss_out = loss;
    }
}

__global__ __launch_bounds__(64) void k_ctc_slow(const float* __restrict__ logits,
                                                 const int* __restrict__ text_lens,
                                                 const int* __restrict__ mel_lens,
                                                 const float* __restrict__ lsums,
                                                 float* __restrict__ losses) {
    const int b  = blockIdx.x;
    const int tl = text_lens[b];
    const int ml = mel_lens[b];
    const float lsum = lsums[b];
    const float* Lb = logits + (size_t)b * T_ * C_;
    float* lo = losses + b;
    const int PP = (tl + 1 + 63) >> 6;
    switch (PP) {
        case 1: ctc_run_slow<1>(Lb, lsum, tl, ml, lo); break;
        case 2: ctc_run_slow<2>(Lb, lsum, tl, ml, lo); break;
        case 3: ctc_run_slow<3>(Lb, lsum, tl, ml, lo); break;
        case 4: ctc_run_slow<4>(Lb, lsum, tl, ml, lo); break;
        case 5: ctc_run_slow<5>(Lb, lsum, tl, ml, lo); break;
        case 6: ctc_run_slow<6>(Lb, lsum, tl, ml, lo); break;
        default: ctc_run_slow<7>(Lb, lsum, tl, ml, lo); break;
    }
}

// ---------------- Pass C: deterministic mean ----------------
__global__ __launch_bounds__(64) void k_final(const float* __restrict__ losses,
                                              float* __restrict__ out) {
    const int lane = threadIdx.x;
    float v = (lane < B_) ? losses[lane] : 0.f;
#pragma unroll
    for (int off = 32; off; off >>= 1) v += __shfl_xor(v, off);
    if (lane == 0) out[0] = v * (1.0f / B_);
}

extern "C" void kernel_launch(void* const* d_in, const int* in_sizes, int n_in,
                              void* d_out, int out_size, void* d_ws, size_t ws_size,
                              hipStream_t stream) {
    const float* logits    = (const float*)d_in[0];   // [B,1,T,C] fp32
    const int*   text_lens = (const int*)d_in[1];     // [B] int32
    const int*   mel_lens  = (const int*)d_in[2];     // [B] int32
    float* out = (float*)d_out;

    const size_t PBF_BYTES = (size_t)B_ * T_ * 512 * 2;           // 65,536,000
    const size_t need = PBF_BYTES + (size_t)B_ * T_ * 4 + 2 * B_ * 4 + 64;

    if (ws_size >= need) {
        unsigned short* pbf = (unsigned short*)d_ws;
        float* ls     = (float*)((char*)d_ws + PBF_BYTES);
        float* lsums  = ls + (size_t)B_ * T_;
        float* losses = lsums + B_;
        k_prob<<<B_ * T_ / 4, 256, 0, stream>>>(logits, text_lens, pbf, ls);
        k_ctc_fast<<<B_, 64, 0, stream>>>(pbf, text_lens, mel_lens, losses);
        k_final<<<1, 64, 0, stream>>>(losses, out);
    } else {
        float* ls     = (float*)d_ws;
        float* lsums  = ls + (size_t)B_ * T_;
        float* losses = lsums + B_;
        k_prob<<<B_ * T_ / 4, 256, 0, stream>>>(logits, text_lens, nullptr, ls);
        k_lsum<<<B_, 256, 0, stream>>>(ls, mel_lens, lsums);
        k_ctc_slow<<<B_, 64, 0, stream>>>(logits, text_lens, mel_lens, lsums, losses);
        k_final<<<1, 64, 0, stream>>>(losses, out);
    }
}

// Round 9
// 213.258 us; speedup vs baseline: 4.8594x; 1.0768x over previous
//
#include <hip/hip_runtime.h>

// ForwardSumLossWithBlank: CTC forward (alpha) loss, blank=0, targets=arange(text_len).
// B=32, T=2000 mel frames, C=400 classes. Output: scalar mean loss (fp32).
//
// FAST path (needs ~66 MB of d_ws):
//   Pass A (k_prob): masked NORMALIZED probs -> bf16 padded [T][512] in ws. In fast
//          mode the `ls` buffer holds p0[t] (f32 blank prob) instead of ln(sum) —
//          consumed by k_ctc_fast via SCALAR loads (off the VALU cadence).
//   Pass B (k_ctc_fast): one wave per sample, uniform 8 pairs/lane. Per step: ONE
//          saddr-form global_load_dwordx4 (16-deep ring, uniform row pointer ->
//          SALU addressing), bf16 converts pipelined one step ahead (pA/pB), p0
//          scalar-loaded two steps ahead, 32-op banded update, 1 DPP neighbor.
//          Renorm every 8 steps, fresh, exponent-only (exact pow2, integer lognorm),
//          local max via v_max3 tree.
//   Pass C (k_final): deterministic mean.
// FALLBACK path (small ws): proven R4 kernels (raw exp(logits), -lsum epilogue).

static constexpr int B_ = 32;
static constexpr int T_ = 2000;
static constexpr int C_ = 400;
static constexpr float M0f    = 1e20f;
static constexpr float LOGM0f = 46.05170186f;   // ln(1e20) (fallback path)

template <int CTRL>
__device__ __forceinline__ float dppmov(float v) {
    // mov_dpp, bound_ctrl=1: invalid-source lanes read 0 (safe: alphas >= 0).
    return __int_as_float(__builtin_amdgcn_update_dpp(
        0, __float_as_int(v), CTRL, 0xF, 0xF, true));
}

__device__ __forceinline__ float bcast0(float v) {
    return __int_as_float(__builtin_amdgcn_readfirstlane(__float_as_int(v)));
}

__device__ __forceinline__ unsigned bf16rne(float f) {
    unsigned u = __float_as_uint(f);
    u += 0x7FFFu + ((u >> 16) & 1u);
    return u >> 16;
}

// ---------------- Pass A: masked normalized probs (bf16, padded 512) ----------------
// fast mode (pbf!=null): ls[row] = p0 (f32 normalized blank prob)
// fallback   (pbf==null): ls[row] = ln(sum exp)
__global__ __launch_bounds__(256) void k_prob(const float* __restrict__ logits,
                                              const int* __restrict__ text_lens,
                                              unsigned short* __restrict__ pbf,
                                              float* __restrict__ ls) {
    const int lane = threadIdx.x & 63;
    const int row  = blockIdx.x * 4 + (threadIdx.x >> 6);   // grid = B*T/4 exactly
    const int b    = row / T_;
    const int tl   = text_lens[b];
    const float* __restrict__ r = logits + (size_t)row * C_;

    const int c0 = lane * 8;
    float v[8];
    if (c0 < C_) {           // row is 1600 B, 16B-aligned; lane<50 reads [c0, c0+8)
        const float4 a = *(const float4*)(r + c0);
        const float4 c = *(const float4*)(r + c0 + 4);
        v[0]=a.x; v[1]=a.y; v[2]=a.z; v[3]=a.w; v[4]=c.x; v[5]=c.y; v[6]=c.z; v[7]=c.w;
    } else {
#pragma unroll
        for (int e = 0; e < 8; ++e) v[e] = 0.f;             // masked below anyway
    }
    float ex[8]; float s = 0.f;
#pragma unroll
    for (int e = 0; e < 8; ++e) {
        const int c = c0 + e;
        const float t = (c < tl) ? __expf(v[e]) : 0.f;      // tl <= 400 -> cols>=400 masked
        ex[e] = t; s += t;
    }
#pragma unroll
    for (int off = 32; off; off >>= 1) s += __shfl_xor(s, off);

    if (pbf) {
        const float inv = 1.0f / s;
        uint4 st;
        st.x = bf16rne(ex[0]*inv) | (bf16rne(ex[1]*inv) << 16);
        st.y = bf16rne(ex[2]*inv) | (bf16rne(ex[3]*inv) << 16);
        st.z = bf16rne(ex[4]*inv) | (bf16rne(ex[5]*inv) << 16);
        st.w = bf16rne(ex[6]*inv) | (bf16rne(ex[7]*inv) << 16);
        *(uint4*)(pbf + (size_t)row * 512 + c0) = st;       // coalesced 1 KB/wave
        if (lane == 0) ls[row] = ex[0] * inv;               // p0 (col 0 always < tl)
    } else {
        if (lane == 0) ls[row] = __logf(s);
    }
}

// ---------------- Pass A2 (fallback only): per-sample sum of ln-denominators ----------------
__global__ __launch_bounds__(256) void k_lsum(const float* __restrict__ ls,
                                              const int* __restrict__ mel_lens,
                                              float* __restrict__ lsums) {
    const int b  = blockIdx.x;
    const int ml = mel_lens[b];
    float s = 0.f;
    for (int i = threadIdx.x; i < ml; i += 256) s += ls[(size_t)b * T_ + i];
#pragma unroll
    for (int off = 32; off; off >>= 1) s += __shfl_xor(s, off);
    __shared__ float ws[4];
    if ((threadIdx.x & 63) == 0) ws[threadIdx.x >> 6] = s;
    __syncthreads();
    if (threadIdx.x == 0) lsums[b] = (ws[0] + ws[1]) + (ws[2] + ws[3]);
}

// ---------------- shared recursion pieces ----------------
// Pair k holds states (2k, 2k+1); pair tl holds only the final even state 2*tl.
//   e = a[2k] + a[2k-1];  a'[2k] = e*p0;  a'[2k+1] = (a[2k+1]+e)*pk
template <int PP>
__device__ __forceinline__ void step_update(const float p0, const float* __restrict__ p,
                                            float* __restrict__ aeven, float* __restrict__ aodd) {
    float prev = dppmov<0x138>(aodd[PP - 1]);   // wave_shr:1; lane0 reads 0
#pragma unroll
    for (int j = 0; j < PP; ++j) {
        const float oldodd = aodd[j];
        const float e = aeven[j] + prev;
        aeven[j] = e * p0;
        aodd[j]  = (oldodd + e) * p[j];
        prev = oldodd;
    }
}

// Fresh exponent-only renorm: local max via v_max3 tree, 6 DPP levels, readlane,
// scale = exact 2^(66-ex) pins post-apply max in [2^66,2^67), integer lognorm.
__device__ __forceinline__ void renorm_exp(float* __restrict__ ae,
                                           float* __restrict__ ao, int& exacc) {
    const float t0 = fmaxf(fmaxf(ae[0], ao[0]), ae[1]);   // v_max3
    const float t1 = fmaxf(fmaxf(ao[1], ae[2]), ao[2]);
    const float t2 = fmaxf(fmaxf(ae[3], ao[3]), ae[4]);
    const float t3 = fmaxf(fmaxf(ao[4], ae[5]), ao[5]);
    const float t4 = fmaxf(fmaxf(ae[6], ao[6]), ae[7]);
    float m = fmaxf(fmaxf(fmaxf(t0, t1), t2), fmaxf(fmaxf(t3, t4), ao[7]));
    m = fmaxf(m, dppmov<0x111>(m));   // row_shr:1
    m = fmaxf(m, dppmov<0x112>(m));   // row_shr:2
    m = fmaxf(m, dppmov<0x114>(m));   // row_shr:4
    m = fmaxf(m, dppmov<0x118>(m));   // row_shr:8
    m = fmaxf(m, dppmov<0x142>(m));   // row_bcast:15
    m = fmaxf(m, dppmov<0x143>(m));   // row_bcast:31 -> lane 63 holds wave max
    const int wmb = __builtin_amdgcn_readlane(__float_as_int(m), 63);
    int ex = ((wmb >> 23) & 0xFF) - 127;
    if (ex < -60) ex = -60;                 // guard vs denorm/zero max
    exacc += ex - 66;
    const float scale = __int_as_float((unsigned)(193 - ex) << 23);  // 2^(66-ex), exact
#pragma unroll
    for (int j = 0; j < 8; ++j) { ae[j] *= scale; ao[j] *= scale; }
}

// old single-shot renorm (fallback path only)
template <int PP>
__device__ __forceinline__ void renorm(float* __restrict__ aeven, float* __restrict__ aodd,
                                       float& lognorm) {
    float m = 0.f;
#pragma unroll
    for (int j = 0; j < PP; ++j) m = fmaxf(m, fmaxf(aeven[j], aodd[j]));
    m = fmaxf(m, dppmov<0x111>(m));
    m = fmaxf(m, dppmov<0x112>(m));
    m = fmaxf(m, dppmov<0x114>(m));
    m = fmaxf(m, dppmov<0x118>(m));
    m = fmaxf(m, dppmov<0x142>(m));
    m = fmaxf(m, dppmov<0x143>(m));
    const float wm  = __int_as_float(__builtin_amdgcn_readlane(__float_as_int(m), 63));
    const float inv = 1.0f / wm;
    lognorm += __logf(wm) - LOGM0f;
#pragma unroll
    for (int j = 0; j < PP; ++j) {
        aeven[j] = (aeven[j] * inv) * M0f;
        aodd[j]  = (aodd[j]  * inv) * M0f;
    }
}

// ---------------- Pass B (fast): bf16 normalized probs, uniform 8 pairs/lane ----------------
__global__ __launch_bounds__(64) void k_ctc_fast(const unsigned short* __restrict__ pbf,
                                                 const int* __restrict__ text_lens,
                                                 const int* __restrict__ mel_lens,
                                                 const float* __restrict__ p0arr,
                                                 float* __restrict__ losses) {
    const int b    = blockIdx.x;
    const int lane = threadIdx.x;
    const int tl   = text_lens[b];
    const int ml   = mel_lens[b];
    const unsigned short* __restrict__ pb = pbf + (size_t)b * T_ * 512;
    const uint4* __restrict__ base = (const uint4*)pb;       // 64 uint4 per row
    const float* __restrict__ p0b  = p0arr + (size_t)b * T_;

    // 16-deep rotating register ring; prologue loads rows 1..16 (ml >= 1024).
    // Uniform row pointer + [lane] -> saddr-form loads (SALU addressing).
    uint4 raw[16];
#pragma unroll
    for (int s = 0; s < 16; ++s) {
        const uint4* __restrict__ rowp = base + (size_t)(s + 1) * 64;
        raw[s] = rowp[lane];
    }

    float aeven[8], aodd[8];
#pragma unroll
    for (int j = 0; j < 8; ++j) { aeven[j] = 0.f; aodd[j] = 0.f; }
    {   // alpha0[0] = alpha0[1] = p(t=0, class 0), pre-scaled by 2^66
        const float p00 = p0b[0] * 0x1p66f;
        if (lane == 0) { aeven[0] = p00; aodd[0] = p00; }
    }
    int exacc = -66;                  // lognorm = exacc * ln2 at the end

#define CVT8(SLOT, P)  { const uint4 w = raw[SLOT];                                   \
        P[0]=__uint_as_float(w.x<<16); P[1]=__uint_as_float(w.x&0xFFFF0000u);         \
        P[2]=__uint_as_float(w.y<<16); P[3]=__uint_as_float(w.y&0xFFFF0000u);         \
        P[4]=__uint_as_float(w.z<<16); P[5]=__uint_as_float(w.z&0xFFFF0000u);         \
        P[6]=__uint_as_float(w.w<<16); P[7]=__uint_as_float(w.w&0xFFFF0000u); }

    float pA[8], pB[8];
    float p0A = p0b[1], p0B = p0b[2];   // scalar loads (uniform index), 2-step pipeline
    CVT8(0, pA)                          // row 1 (= first consumed row)

    // STEP_MAIN(S): consume row tb+S (PIN, P0IN); reload slot S with row tb+S+16
    // (saddr form); CVT slot S+1 for next step; refill P0IN with p0 of row tb+S+2
    // (use-then-overwrite: slot parity repeats every 2, distance 2).
#define STEP_MAIN(S, PIN, P0IN, POUT, CLAMPED)                                 \
    { int tr = tb + (S) + 16;                                                  \
      if (CLAMPED) { if (tr > ml - 1) tr = ml - 1; }                           \
      const uint4* __restrict__ rowp = base + (size_t)tr * 64;                 \
      raw[S] = rowp[lane]; }                                                   \
    CVT8(((S) + 1) & 15, POUT)                                                 \
    step_update<8>(P0IN, PIN, aeven, aodd);                                    \
    { int t2 = tb + (S) + 2;                                                   \
      if (CLAMPED) { if (t2 > ml - 1) t2 = ml - 1; }                           \
      P0IN = p0b[t2]; }                                                        \
    if (((S) & 7) == 7) renorm_exp(aeven, aodd, exacc);

#define BLOCK16(CLAMPED)                                                       \
        STEP_MAIN(0,  pA, p0A, pB, CLAMPED)                                    \
        STEP_MAIN(1,  pB, p0B, pA, CLAMPED)                                    \
        STEP_MAIN(2,  pA, p0A, pB, CLAMPED)                                    \
        STEP_MAIN(3,  pB, p0B, pA, CLAMPED)                                    \
        STEP_MAIN(4,  pA, p0A, pB, CLAMPED)                                    \
        STEP_MAIN(5,  pB, p0B, pA, CLAMPED)                                    \
        STEP_MAIN(6,  pA, p0A, pB, CLAMPED)                                    \
        STEP_MAIN(7,  pB, p0B, pA, CLAMPED)                                    \
        STEP_MAIN(8,  pA, p0A, pB, CLAMPED)                                    \
        STEP_MAIN(9,  pB, p0B, pA, CLAMPED)                                    \
        STEP_MAIN(10, pA, p0A, pB, CLAMPED)                                    \
        STEP_MAIN(11, pB, p0B, pA, CLAMPED)                                    \
        STEP_MAIN(12, pA, p0A, pB, CLAMPED)                                    \
        STEP_MAIN(13, pB, p0B, pA, CLAMPED)                                    \
        STEP_MAIN(14, pA, p0A, pB, CLAMPED)                                    \
        STEP_MAIN(15, pB, p0B, pA, CLAMPED)

    int tb = 1;
    for (; tb + 32 <= ml; tb += 16) {       // steady state: no clamps at all
        BLOCK16(0)
    }
    if (tb + 16 <= ml) {                    // one transition block with clamps
        BLOCK16(1)
        tb += 16;
    }

    // tail: rows tb..ml-1 (<16) resident; p0 slots were refilled with clamped
    // indices that equal the true row while tb+S < ml. No renorm needed
    // (p<=1: shrink-only, <=15 steps of drift stays in fp32 range).
#define STEP_TAIL(S, PIN, P0IN, POUT)                                          \
    if (tb + (S) < ml) {                                                       \
        CVT8(((S) + 1) & 15, POUT)                                             \
        step_update<8>(P0IN, PIN, aeven, aodd);                                \
        { int t2 = tb + (S) + 2; if (t2 > ml - 1) t2 = ml - 1;                 \
          P0IN = p0b[t2]; }                                                    \
    }
    STEP_TAIL(0,  pA, p0A, pB)
    STEP_TAIL(1,  pB, p0B, pA)
    STEP_TAIL(2,  pA, p0A, pB)
    STEP_TAIL(3,  pB, p0B, pA)
    STEP_TAIL(4,  pA, p0A, pB)
    STEP_TAIL(5,  pB, p0B, pA)
    STEP_TAIL(6,  pA, p0A, pB)
    STEP_TAIL(7,  pB, p0B, pA)
    STEP_TAIL(8,  pA, p0A, pB)
    STEP_TAIL(9,  pB, p0B, pA)
    STEP_TAIL(10, pA, p0A, pB)
    STEP_TAIL(11, pB, p0B, pA)
    STEP_TAIL(12, pA, p0A, pB)
    STEP_TAIL(13, pB, p0B, pA)
    STEP_TAIL(14, pA, p0A, pB)
    STEP_TAIL(15, pB, p0B, pA)
#undef STEP_TAIL
#undef BLOCK16
#undef STEP_MAIN
#undef CVT8

    // epilogue: probs are normalized -> ll = ln(contrib) + exacc*ln2
    float contrib = 0.f;
#pragma unroll
    for (int j = 0; j < 8; ++j) {
        const int k = lane * 8 + j;
        if (k == tl)     contrib += aeven[j];
        if (k == tl - 1) contrib += aodd[j];
    }
#pragma unroll
    for (int off = 32; off; off >>= 1) contrib += __shfl_xor(contrib, off);
    if (lane == 0) {
        float loss = 0.f;
        if (contrib > 0.f) {
            const float ll = __logf(contrib) + (float)exacc * 0.69314718056f;
            loss = -ll / (float)tl;
        }
        losses[b] = loss;
    }
}

// ---------------- Pass B (fallback, proven R4): direct logit loads ----------------
template <int PP>
__device__ __forceinline__ void ctc_run_slow(const float* __restrict__ Lb, float lsum,
                                             int tl, int ml, float* __restrict__ loss_out) {
    const int lane = threadIdx.x;
    const int base = lane * PP;
    int   idx[PP];
    float mask[PP];
#pragma unroll
    for (int j = 0; j < PP; ++j) {
        const int k = base + j;
        idx[j]  = (k < C_) ? k : (C_ - 1);
        mask[j] = (k < tl) ? 1.f : 0.f;
    }
    float raw[8][PP];
#pragma unroll
    for (int s = 0; s < 8; ++s) {
        const float* __restrict__ rowp = Lb + (size_t)(s + 1) * C_;
#pragma unroll
        for (int j = 0; j < PP; ++j) raw[s][j] = rowp[idx[j]];
    }
    float aeven[PP], aodd[PP];
#pragma unroll
    for (int j = 0; j < PP; ++j) { aeven[j] = 0.f; aodd[j] = 0.f; }
    {
        const float a00 = __expf(Lb[0]) * M0f;
        if (lane == 0) { aeven[0] = a00; aodd[0] = a00; }
    }
    float lognorm = -LOGM0f;
    int tb = 1;
    for (; tb + 8 <= ml; tb += 8) {
#pragma unroll
        for (int s = 0; s < 8; ++s) {
            const int tt = tb + s;
            const float p0 = __expf(bcast0(raw[s][0]));
            float p[PP];
#pragma unroll
            for (int j = 0; j < PP; ++j) p[j] = __expf(raw[s][j]) * mask[j];
            { int tr = tt + 8; if (tr > ml - 1) tr = ml - 1;
              const float* __restrict__ rowp = Lb + (size_t)tr * C_;
#pragma unroll
              for (int j = 0; j < PP; ++j) raw[s][j] = rowp[idx[j]]; }
            step_update<PP>(p0, p, aeven, aodd);
            if (s == 7) renorm<PP>(aeven, aodd, lognorm);
        }
    }
#pragma unroll
    for (int s = 0; s < 8; ++s) {
        const int tt = tb + s;
        if (tt < ml) {
            const float p0 = __expf(bcast0(raw[s][0]));
            float p[PP];
#pragma unroll
            for (int j = 0; j < PP; ++j) p[j] = __expf(raw[s][j]) * mask[j];
            step_update<PP>(p0, p, aeven, aodd);
            if (s == 7) renorm<PP>(aeven, aodd, lognorm);
        }
    }
    float contrib = 0.f;
#pragma unroll
    for (int j = 0; j < PP; ++j) {
        const int k = base + j;
        if (k == tl)     contrib += aeven[j];
        if (k == tl - 1) contrib += aodd[j];
    }
#pragma unroll
    for (int off = 32; off; off >>= 1) contrib += __shfl_xor(contrib, off);
    if (lane == 0) {
        float loss = 0.f;
        if (contrib > 0.f) {
            const float ll = __logf(contrib) + lognorm - lsum;   // raw domain: -lsum needed
            loss = -ll / (float)tl;
        }
        *loss_out = loss;
    }
}

__global__ __launch_bounds__(64) void k_ctc_slow(const float* __restrict__ logits,
                                                 const int* __restrict__ text_lens,
                                                 const int* __restrict__ mel_lens,
                                                 const float* __restrict__ lsums,
                                                 float* __restrict__ losses) {
    const int b  = blockIdx.x;
    const int tl = text_lens[b];
    const int ml = mel_lens[b];
    const float lsum = lsums[b];
    const float* Lb = logits + (size_t)b * T_ * C_;
    float* lo = losses + b;
    const int PP = (tl + 1 + 63) >> 6;
    switch (PP) {
        case 1: ctc_run_slow<1>(Lb, lsum, tl, ml, lo); break;
        case 2: ctc_run_slow<2>(Lb, lsum, tl, ml, lo); break;
        case 3: ctc_run_slow<3>(Lb, lsum, tl, ml, lo); break;
        case 4: ctc_run_slow<4>(Lb, lsum, tl, ml, lo); break;
        case 5: ctc_run_slow<5>(Lb, lsum, tl, ml, lo); break;
        case 6: ctc_run_slow<6>(Lb, lsum, tl, ml, lo); break;
        default: ctc_run_slow<7>(Lb, lsum, tl, ml, lo); break;
    }
}

// ---------------- Pass C: deterministic mean ----------------
__global__ __launch_bounds__(64) void k_final(const float* __restrict__ losses,
                                              float* __restrict__ out) {
    const int lane = threadIdx.x;
    float v = (lane < B_) ? losses[lane] : 0.f;
#pragma unroll
    for (int off = 32; off; off >>= 1) v += __shfl_xor(v, off);
    if (lane == 0) out[0] = v * (1.0f / B_);
}

extern "C" void kernel_launch(void* const* d_in, const int* in_sizes, int n_in,
                              void* d_out, int out_size, void* d_ws, size_t ws_size,
                              hipStream_t stream) {
    const float* logits    = (const float*)d_in[0];   // [B,1,T,C] fp32
    const int*   text_lens = (const int*)d_in[1];     // [B] int32
    const int*   mel_lens  = (const int*)d_in[2];     // [B] int32
    float* out = (float*)d_out;

    const size_t PBF_BYTES = (size_t)B_ * T_ * 512 * 2;           // 65,536,000
    const size_t need = PBF_BYTES + (size_t)B_ * T_ * 4 + 2 * B_ * 4 + 64;

    if (ws_size >= need) {
        unsigned short* pbf = (unsigned short*)d_ws;
        float* ls     = (float*)((char*)d_ws + PBF_BYTES);   // holds p0[t] in fast mode
        float* lsums  = ls + (size_t)B_ * T_;
        float* losses = lsums + B_;
        k_prob<<<B_ * T_ / 4, 256, 0, stream>>>(logits, text_lens, pbf, ls);
        k_ctc_fast<<<B_, 64, 0, stream>>>(pbf, text_lens, mel_lens, ls, losses);
        k_final<<<1, 64, 0, stream>>>(losses, out);
    } else {
        float* ls     = (float*)d_ws;
        float* lsums  = ls + (size_t)B_ * T_;
        float* losses = lsums + B_;
        k_prob<<<B_ * T_ / 4, 256, 0, stream>>>(logits, text_lens, nullptr, ls);
        k_lsum<<<B_, 256, 0, stream>>>(ls, mel_lens, lsums);
        k_ctc_slow<<<B_, 64, 0, stream>>>(logits, text_lens, mel_lens, lsums, losses);
        k_final<<<1, 64, 0, stream>>>(losses, out);
    }
}

// Round 10
// 168.774 us; speedup vs baseline: 6.1401x; 1.2636x over previous
//
#include <hip/hip_runtime.h>

// ForwardSumLossWithBlank: CTC forward (alpha) loss, blank=0, targets=arange(text_len).
// B=32, T=2000 mel frames, C=400 classes. Output: scalar mean loss (fp32).
//
// FAST path (needs ~66 MB of d_ws):
//   Pass A (k_prob): masked NORMALIZED probs -> bf16 [T][512] in ws, PERMUTED so each
//          lane's 8 columns are stored as halfword pairs (c,c+4),(c+1,c+5),(c+2,c+6),
//          (c+3,c+7) — feeds the packed-FP32 recursion with zero repacking. `ls`
//          holds p0[t] f32 (scalar-loaded by pass B).
//   Pass B (k_ctc_fast): one wave per sample, 8 pairs/lane as 4 x float2 slots
//          (slot j = CTC pairs lane*8+j and lane*8+4+j). Per step: ONE saddr-form
//          global_load_dwordx4 (16-deep ring), 8 CVT shifts pipelined one step ahead,
//          packed v_pk_add/mul_f32 update (16 packed ops vs 32 scalar; prev operand
//          for slot j is old Ao[j-1] — register-aligned by construction; slot 0:
//          1 DPP + 1 mov), p0 scalar-loaded 2 steps ahead. Renorm every 8 steps,
//          fresh, exponent-only, packed max tree + packed scale.
//   Pass C (k_final): deterministic mean.
// FALLBACK path (small ws): proven R4 kernels (raw exp(logits), -lsum epilogue).

static constexpr int B_ = 32;
static constexpr int T_ = 2000;
static constexpr int C_ = 400;
static constexpr float M0f    = 1e20f;
static constexpr float LOGM0f = 46.05170186f;   // ln(1e20) (fallback path)

typedef float f32x2 __attribute__((ext_vector_type(2)));

template <int CTRL>
__device__ __forceinline__ float dppmov(float v) {
    // mov_dpp, bound_ctrl=1: invalid-source lanes read 0 (safe: alphas >= 0).
    return __int_as_float(__builtin_amdgcn_update_dpp(
        0, __float_as_int(v), CTRL, 0xF, 0xF, true));
}

__device__ __forceinline__ float bcast0(float v) {
    return __int_as_float(__builtin_amdgcn_readfirstlane(__float_as_int(v)));
}

__device__ __forceinline__ unsigned bf16rne(float f) {
    unsigned u = __float_as_uint(f);
    u += 0x7FFFu + ((u >> 16) & 1u);
    return u >> 16;
}

// ---------------- Pass A: masked normalized probs (bf16, padded 512, permuted) ----------------
// fast mode (pbf!=null): ls[row] = p0 (f32 normalized blank prob)
// fallback   (pbf==null): ls[row] = ln(sum exp)
__global__ __launch_bounds__(256) void k_prob(const float* __restrict__ logits,
                                              const int* __restrict__ text_lens,
                                              unsigned short* __restrict__ pbf,
                                              float* __restrict__ ls) {
    const int lane = threadIdx.x & 63;
    const int row  = blockIdx.x * 4 + (threadIdx.x >> 6);   // grid = B*T/4 exactly
    const int b    = row / T_;
    const int tl   = text_lens[b];
    const float* __restrict__ r = logits + (size_t)row * C_;

    const int c0 = lane * 8;
    float v[8];
    if (c0 < C_) {           // row is 1600 B, 16B-aligned; lane<50 reads [c0, c0+8)
        const float4 a = *(const float4*)(r + c0);
        const float4 c = *(const float4*)(r + c0 + 4);
        v[0]=a.x; v[1]=a.y; v[2]=a.z; v[3]=a.w; v[4]=c.x; v[5]=c.y; v[6]=c.z; v[7]=c.w;
    } else {
#pragma unroll
        for (int e = 0; e < 8; ++e) v[e] = 0.f;             // masked below anyway
    }
    float ex[8]; float s = 0.f;
#pragma unroll
    for (int e = 0; e < 8; ++e) {
        const int c = c0 + e;
        const float t = (c < tl) ? __expf(v[e]) : 0.f;      // tl <= 400 -> cols>=400 masked
        ex[e] = t; s += t;
    }
#pragma unroll
    for (int off = 32; off; off >>= 1) s += __shfl_xor(s, off);

    if (pbf) {
        const float inv = 1.0f / s;
        // PERMUTED store: halfword pair (col e, col e+4) -> dword e, e=0..3.
        uint4 st;
        st.x = bf16rne(ex[0]*inv) | (bf16rne(ex[4]*inv) << 16);
        st.y = bf16rne(ex[1]*inv) | (bf16rne(ex[5]*inv) << 16);
        st.z = bf16rne(ex[2]*inv) | (bf16rne(ex[6]*inv) << 16);
        st.w = bf16rne(ex[3]*inv) | (bf16rne(ex[7]*inv) << 16);
        *(uint4*)(pbf + (size_t)row * 512 + c0) = st;       // coalesced 1 KB/wave
        if (lane == 0) ls[row] = ex[0] * inv;               // p0 (col 0 always < tl)
    } else {
        if (lane == 0) ls[row] = __logf(s);
    }
}

// ---------------- Pass A2 (fallback only): per-sample sum of ln-denominators ----------------
__global__ __launch_bounds__(256) void k_lsum(const float* __restrict__ ls,
                                              const int* __restrict__ mel_lens,
                                              float* __restrict__ lsums) {
    const int b  = blockIdx.x;
    const int ml = mel_lens[b];
    float s = 0.f;
    for (int i = threadIdx.x; i < ml; i += 256) s += ls[(size_t)b * T_ + i];
#pragma unroll
    for (int off = 32; off; off >>= 1) s += __shfl_xor(s, off);
    __shared__ float ws[4];
    if ((threadIdx.x & 63) == 0) ws[threadIdx.x >> 6] = s;
    __syncthreads();
    if (threadIdx.x == 0) lsums[b] = (ws[0] + ws[1]) + (ws[2] + ws[3]);
}

// ---------------- packed recursion pieces (fast path) ----------------
// Slot j holds CTC pairs (lane*8+j, lane*8+4+j) as float2 (X=low pair, Y=high pair).
//   e = ae + prev;  ae' = e*p0;  ao' = (ao + e) * pk
// prev for slot j>=1 is OLD Ao[j-1] (aligned float2); slot 0 = (dpp(Ao[3].y), Ao[3].x).
__device__ __forceinline__ void step_update_pk(const float p0, const f32x2* __restrict__ pk,
                                               f32x2* __restrict__ Ae, f32x2* __restrict__ Ao) {
    const float bnd = dppmov<0x138>(Ao[3].y);   // wave_shr:1; lane0 reads 0
    f32x2 prev0; prev0.x = bnd; prev0.y = Ao[3].x;
    const f32x2 E0 = Ae[0] + prev0;
    const f32x2 E1 = Ae[1] + Ao[0];
    const f32x2 E2 = Ae[2] + Ao[1];
    const f32x2 E3 = Ae[3] + Ao[2];
    const f32x2 T0 = Ao[0] + E0;
    const f32x2 T1 = Ao[1] + E1;
    const f32x2 T2 = Ao[2] + E2;
    const f32x2 T3 = Ao[3] + E3;
    const f32x2 vp0 = {p0, p0};
    Ae[0] = E0 * vp0; Ae[1] = E1 * vp0; Ae[2] = E2 * vp0; Ae[3] = E3 * vp0;
    Ao[0] = T0 * pk[0]; Ao[1] = T1 * pk[1]; Ao[2] = T2 * pk[2]; Ao[3] = T3 * pk[3];
}

// Fresh exponent-only renorm, packed: pk-max tree + 6 DPP levels + readlane,
// scale = exact 2^(66-ex) pins post-apply max in [2^66,2^67), integer lognorm.
__device__ __forceinline__ void renorm_exp_pk(f32x2* __restrict__ Ae,
                                              f32x2* __restrict__ Ao, int& exacc) {
    const f32x2 m0 = __builtin_elementwise_max(__builtin_elementwise_max(Ae[0], Ao[0]),
                                               __builtin_elementwise_max(Ae[1], Ao[1]));
    const f32x2 m1 = __builtin_elementwise_max(__builtin_elementwise_max(Ae[2], Ao[2]),
                                               __builtin_elementwise_max(Ae[3], Ao[3]));
    const f32x2 m2 = __builtin_elementwise_max(m0, m1);
    float m = fmaxf(m2.x, m2.y);
    m = fmaxf(m, dppmov<0x111>(m));   // row_shr:1
    m = fmaxf(m, dppmov<0x112>(m));   // row_shr:2
    m = fmaxf(m, dppmov<0x114>(m));   // row_shr:4
    m = fmaxf(m, dppmov<0x118>(m));   // row_shr:8
    m = fmaxf(m, dppmov<0x142>(m));   // row_bcast:15
    m = fmaxf(m, dppmov<0x143>(m));   // row_bcast:31 -> lane 63 holds wave max
    const int wmb = __builtin_amdgcn_readlane(__float_as_int(m), 63);
    int ex = ((wmb >> 23) & 0xFF) - 127;
    if (ex < -60) ex = -60;                 // guard vs denorm/zero max
    exacc += ex - 66;
    const float scale = __int_as_float((unsigned)(193 - ex) << 23);  // 2^(66-ex), exact
    const f32x2 sc = {scale, scale};
#pragma unroll
    for (int j = 0; j < 4; ++j) { Ae[j] *= sc; Ao[j] *= sc; }
}

// ---------------- scalar recursion pieces (fallback path, proven R4) ----------------
template <int PP>
__device__ __forceinline__ void step_update(const float p0, const float* __restrict__ p,
                                            float* __restrict__ aeven, float* __restrict__ aodd) {
    float prev = dppmov<0x138>(aodd[PP - 1]);
#pragma unroll
    for (int j = 0; j < PP; ++j) {
        const float oldodd = aodd[j];
        const float e = aeven[j] + prev;
        aeven[j] = e * p0;
        aodd[j]  = (oldodd + e) * p[j];
        prev = oldodd;
    }
}

template <int PP>
__device__ __forceinline__ void renorm(float* __restrict__ aeven, float* __restrict__ aodd,
                                       float& lognorm) {
    float m = 0.f;
#pragma unroll
    for (int j = 0; j < PP; ++j) m = fmaxf(m, fmaxf(aeven[j], aodd[j]));
    m = fmaxf(m, dppmov<0x111>(m));
    m = fmaxf(m, dppmov<0x112>(m));
    m = fmaxf(m, dppmov<0x114>(m));
    m = fmaxf(m, dppmov<0x118>(m));
    m = fmaxf(m, dppmov<0x142>(m));
    m = fmaxf(m, dppmov<0x143>(m));
    const float wm  = __int_as_float(__builtin_amdgcn_readlane(__float_as_int(m), 63));
    const float inv = 1.0f / wm;
    lognorm += __logf(wm) - LOGM0f;
#pragma unroll
    for (int j = 0; j < PP; ++j) {
        aeven[j] = (aeven[j] * inv) * M0f;
        aodd[j]  = (aodd[j]  * inv) * M0f;
    }
}

// ---------------- Pass B (fast): permuted bf16 probs, packed-FP32 recursion ----------------
__global__ __launch_bounds__(64) void k_ctc_fast(const unsigned short* __restrict__ pbf,
                                                 const int* __restrict__ text_lens,
                                                 const int* __restrict__ mel_lens,
                                                 const float* __restrict__ p0arr,
                                                 float* __restrict__ losses) {
    const int b    = blockIdx.x;
    const int lane = threadIdx.x;
    const int tl   = text_lens[b];
    const int ml   = mel_lens[b];
    const unsigned short* __restrict__ pb = pbf + (size_t)b * T_ * 512;
    const uint4* __restrict__ base = (const uint4*)pb;       // 64 uint4 per row
    const float* __restrict__ p0b  = p0arr + (size_t)b * T_;

    // 16-deep rotating register ring; prologue loads rows 1..16 (ml >= 1024).
    uint4 raw[16];
#pragma unroll
    for (int s = 0; s < 16; ++s) {
        const uint4* __restrict__ rowp = base + (size_t)(s + 1) * 64;
        raw[s] = rowp[lane];
    }

    f32x2 Ae[4], Ao[4];
#pragma unroll
    for (int j = 0; j < 4; ++j) { Ae[j] = (f32x2){0.f, 0.f}; Ao[j] = (f32x2){0.f, 0.f}; }
    {   // alpha0[0] = alpha0[1] = p(t=0, class 0), pre-scaled by 2^66; pair 0 = slot0.x
        const float p00 = p0b[0] * 0x1p66f;
        if (lane == 0) { Ae[0].x = p00; Ao[0].x = p00; }
    }
    int exacc = -66;                  // lognorm = exacc * ln2 at the end

    // permuted layout: dword e of w = halfword pair (col e, col e+4) = slot e
#define CVT8(SLOT, P)  { const uint4 w = raw[SLOT];                                   \
        P[0].x=__uint_as_float(w.x<<16); P[0].y=__uint_as_float(w.x&0xFFFF0000u);     \
        P[1].x=__uint_as_float(w.y<<16); P[1].y=__uint_as_float(w.y&0xFFFF0000u);     \
        P[2].x=__uint_as_float(w.z<<16); P[2].y=__uint_as_float(w.z&0xFFFF0000u);     \
        P[3].x=__uint_as_float(w.w<<16); P[3].y=__uint_as_float(w.w&0xFFFF0000u); }

    f32x2 pA[4], pB[4];
    float p0A = p0b[1], p0B = p0b[2];   // scalar loads (uniform index), 2-step pipeline
    CVT8(0, pA)                          // row 1 (= first consumed row)

#define STEP_MAIN(S, PIN, P0IN, POUT, CLAMPED)                                 \
    { int tr = tb + (S) + 16;                                                  \
      if (CLAMPED) { if (tr > ml - 1) tr = ml - 1; }                           \
      const uint4* __restrict__ rowp = base + (size_t)tr * 64;                 \
      raw[S] = rowp[lane]; }                                                   \
    CVT8(((S) + 1) & 15, POUT)                                                 \
    step_update_pk(P0IN, PIN, Ae, Ao);                                         \
    { int t2 = tb + (S) + 2;                                                   \
      if (CLAMPED) { if (t2 > ml - 1) t2 = ml - 1; }                           \
      P0IN = p0b[t2]; }                                                        \
    if (((S) & 7) == 7) renorm_exp_pk(Ae, Ao, exacc);

#define BLOCK16(CLAMPED)                                                       \
        STEP_MAIN(0,  pA, p0A, pB, CLAMPED)                                    \
        STEP_MAIN(1,  pB, p0B, pA, CLAMPED)                                    \
        STEP_MAIN(2,  pA, p0A, pB, CLAMPED)                                    \
        STEP_MAIN(3,  pB, p0B, pA, CLAMPED)                                    \
        STEP_MAIN(4,  pA, p0A, pB, CLAMPED)                                    \
        STEP_MAIN(5,  pB, p0B, pA, CLAMPED)                                    \
        STEP_MAIN(6,  pA, p0A, pB, CLAMPED)                                    \
        STEP_MAIN(7,  pB, p0B, pA, CLAMPED)                                    \
        STEP_MAIN(8,  pA, p0A, pB, CLAMPED)                                    \
        STEP_MAIN(9,  pB, p0B, pA, CLAMPED)                                    \
        STEP_MAIN(10, pA, p0A, pB, CLAMPED)                                    \
        STEP_MAIN(11, pB, p0B, pA, CLAMPED)                                    \
        STEP_MAIN(12, pA, p0A, pB, CLAMPED)                                    \
        STEP_MAIN(13, pB, p0B, pA, CLAMPED)                                    \
        STEP_MAIN(14, pA, p0A, pB, CLAMPED)                                    \
        STEP_MAIN(15, pB, p0B, pA, CLAMPED)

    int tb = 1;
    for (; tb + 32 <= ml; tb += 16) {       // steady state: no clamps at all
        BLOCK16(0)
    }
    if (tb + 16 <= ml) {                    // one transition block with clamps
        BLOCK16(1)
        tb += 16;
    }

    // tail: rows tb..ml-1 (<16) resident; no renorm needed (p<=1: shrink-only,
    // <=15 steps of drift stays in fp32 range).
#define STEP_TAIL(S, PIN, P0IN, POUT)                                          \
    if (tb + (S) < ml) {                                                       \
        CVT8(((S) + 1) & 15, POUT)                                             \
        step_update_pk(P0IN, PIN, Ae, Ao);                                     \
        { int t2 = tb + (S) + 2; if (t2 > ml - 1) t2 = ml - 1;                 \
          P0IN = p0b[t2]; }                                                    \
    }
    STEP_TAIL(0,  pA, p0A, pB)
    STEP_TAIL(1,  pB, p0B, pA)
    STEP_TAIL(2,  pA, p0A, pB)
    STEP_TAIL(3,  pB, p0B, pA)
    STEP_TAIL(4,  pA, p0A, pB)
    STEP_TAIL(5,  pB, p0B, pA)
    STEP_TAIL(6,  pA, p0A, pB)
    STEP_TAIL(7,  pB, p0B, pA)
    STEP_TAIL(8,  pA, p0A, pB)
    STEP_TAIL(9,  pB, p0B, pA)
    STEP_TAIL(10, pA, p0A, pB)
    STEP_TAIL(11, pB, p0B, pA)
    STEP_TAIL(12, pA, p0A, pB)
    STEP_TAIL(13, pB, p0B, pA)
    STEP_TAIL(14, pA, p0A, pB)
    STEP_TAIL(15, pB, p0B, pA)
#undef STEP_TAIL
#undef BLOCK16
#undef STEP_MAIN
#undef CVT8

    // epilogue: probs are normalized -> ll = ln(contrib) + exacc*ln2
    // slot j: X = CTC pair lane*8+j, Y = pair lane*8+4+j
    float contrib = 0.f;
#pragma unroll
    for (int j = 0; j < 4; ++j) {
        const int kx = lane * 8 + j;
        const int ky = kx + 4;
        if (kx == tl)     contrib += Ae[j].x;
        if (kx == tl - 1) contrib += Ao[j].x;
        if (ky == tl)     contrib += Ae[j].y;
        if (ky == tl - 1) contrib += Ao[j].y;
    }
#pragma unroll
    for (int off = 32; off; off >>= 1) contrib += __shfl_xor(contrib, off);
    if (lane == 0) {
        float loss = 0.f;
        if (contrib > 0.f) {
            const float ll = __logf(contrib) + (float)exacc * 0.69314718056f;
            loss = -ll / (float)tl;
        }
        losses[b] = loss;
    }
}

// ---------------- Pass B (fallback, proven R4): direct logit loads ----------------
template <int PP>
__device__ __forceinline__ void ctc_run_slow(const float* __restrict__ Lb, float lsum,
                                             int tl, int ml, float* __restrict__ loss_out) {
    const int lane = threadIdx.x;
    const int base = lane * PP;
    int   idx[PP];
    float mask[PP];
#pragma unroll
    for (int j = 0; j < PP; ++j) {
        const int k = base + j;
        idx[j]  = (k < C_) ? k : (C_ - 1);
        mask[j] = (k < tl) ? 1.f : 0.f;
    }
    float raw[8][PP];
#pragma unroll
    for (int s = 0; s < 8; ++s) {
        const float* __restrict__ rowp = Lb + (size_t)(s + 1) * C_;
#pragma unroll
        for (int j = 0; j < PP; ++j) raw[s][j] = rowp[idx[j]];
    }
    float aeven[PP], aodd[PP];
#pragma unroll
    for (int j = 0; j < PP; ++j) { aeven[j] = 0.f; aodd[j] = 0.f; }
    {
        const float a00 = __expf(Lb[0]) * M0f;
        if (lane == 0) { aeven[0] = a00; aodd[0] = a00; }
    }
    float lognorm = -LOGM0f;
    int tb = 1;
    for (; tb + 8 <= ml; tb += 8) {
#pragma unroll
        for (int s = 0; s < 8; ++s) {
            const int tt = tb + s;
            const float p0 = __expf(bcast0(raw[s][0]));
            float p[PP];
#pragma unroll
            for (int j = 0; j < PP; ++j) p[j] = __expf(raw[s][j]) * mask[j];
            { int tr = tt + 8; if (tr > ml - 1) tr = ml - 1;
              const float* __restrict__ rowp = Lb + (size_t)tr * C_;
#pragma unroll
              for (int j = 0; j < PP; ++j) raw[s][j] = rowp[idx[j]]; }
            step_update<PP>(p0, p, aeven, aodd);
            if (s == 7) renorm<PP>(aeven, aodd, lognorm);
        }
    }
#pragma unroll
    for (int s = 0; s < 8; ++s) {
        const int tt = tb + s;
        if (tt < ml) {
            const float p0 = __expf(bcast0(raw[s][0]));
            float p[PP];
#pragma unroll
            for (int j = 0; j < PP; ++j) p[j] = __expf(raw[s][j]) * mask[j];
            step_update<PP>(p0, p, aeven, aodd);
            if (s == 7) renorm<PP>(aeven, aodd, lognorm);
        }
    }
    float contrib = 0.f;
#pragma unroll
    for (int j = 0; j < PP; ++j) {
        const int k = base + j;
        if (k == tl)     contrib += aeven[j];
        if (k == tl - 1) contrib += aodd[j];
    }
#pragma unroll
    for (int off = 32; off; off >>= 1) contrib += __shfl_xor(contrib, off);
    if (lane == 0) {
        float loss = 0.f;
        if (contrib > 0.f) {
            const float ll = __logf(contrib) + lognorm - lsum;   // raw domain: -lsum needed
            loss = -ll / (float)tl;
        }
        *loss_out = loss;
    }
}

__global__ __launch_bounds__(64) void k_ctc_slow(const float* __restrict__ logits,
                                                 const int* __restrict__ text_lens,
                                                 const int* __restrict__ mel_lens,
                                                 const float* __restrict__ lsums,
                                                 float* __restrict__ losses) {
    const int b  = blockIdx.x;
    const int tl = text_lens[b];
    const int ml = mel_lens[b];
    const float lsum = lsums[b];
    const float* Lb = logits + (size_t)b * T_ * C_;
    float* lo = losses + b;
    const int PP = (tl + 1 + 63) >> 6;
    switch (PP) {
        case 1: ctc_run_slow<1>(Lb, lsum, tl, ml, lo); break;
        case 2: ctc_run_slow<2>(Lb, lsum, tl, ml, lo); break;
        case 3: ctc_run_slow<3>(Lb, lsum, tl, ml, lo); break;
        case 4: ctc_run_slow<4>(Lb, lsum, tl, ml, lo); break;
        case 5: ctc_run_slow<5>(Lb, lsum, tl, ml, lo); break;
        case 6: ctc_run_slow<6>(Lb, lsum, tl, ml, lo); break;
        default: ctc_run_slow<7>(Lb, lsum, tl, ml, lo); break;
    }
}

// ---------------- Pass C: deterministic mean ----------------
__global__ __launch_bounds__(64) void k_final(const float* __restrict__ losses,
                                              float* __restrict__ out) {
    const int lane = threadIdx.x;
    float v = (lane < B_) ? losses[lane] : 0.f;
#pragma unroll
    for (int off = 32; off; off >>= 1) v += __shfl_xor(v, off);
    if (lane == 0) out[0] = v * (1.0f / B_);
}

extern "C" void kernel_launch(void* const* d_in, const int* in_sizes, int n_in,
                              void* d_out, int out_size, void* d_ws, size_t ws_size,
                              hipStream_t stream) {
    const float* logits    = (const float*)d_in[0];   // [B,1,T,C] fp32
    const int*   text_lens = (const int*)d_in[1];     // [B] int32
    const int*   mel_lens  = (const int*)d_in[2];     // [B] int32
    float* out = (float*)d_out;

    const size_t PBF_BYTES = (size_t)B_ * T_ * 512 * 2;           // 65,536,000
    const size_t need = PBF_BYTES + (size_t)B_ * T_ * 4 + 2 * B_ * 4 + 64;

    if (ws_size >= need) {
        unsigned short* pbf = (unsigned short*)d_ws;
        float* ls     = (float*)((char*)d_ws + PBF_BYTES);   // holds p0[t] in fast mode
        float* lsums  = ls + (size_t)B_ * T_;
        float* losses = lsums + B_;
        k_prob<<<B_ * T_ / 4, 256, 0, stream>>>(logits, text_lens, pbf, ls);
        k_ctc_fast<<<B_, 64, 0, stream>>>(pbf, text_lens, mel_lens, ls, losses);
        k_final<<<1, 64, 0, stream>>>(losses, out);
    } else {
        float* ls     = (float*)d_ws;
        float* lsums  = ls + (size_t)B_ * T_;
        float* losses = lsums + B_;
        k_prob<<<B_ * T_ / 4, 256, 0, stream>>>(logits, text_lens, nullptr, ls);
        k_lsum<<<B_, 256, 0, stream>>>(ls, mel_lens, lsums);
        k_ctc_slow<<<B_, 64, 0, stream>>>(logits, text_lens, mel_lens, lsums, losses);
        k_final<<<1, 64, 0, stream>>>(losses, out);
    }
}